// Round 6
// baseline (651.858 us; speedup 1.0000x reference)
//
#include <hip/hip_runtime.h>
#include <hip/hip_bf16.h>

#define L_ 2048
#define D_ 192
#define HK_ 48
#define EPS_ 1e-3f
#define SCALE_ 0.28867513459481287f  // 1/sqrt(12)

typedef __hip_bfloat16 bf16;
typedef _Float16 f16;
typedef _Float16 f16x4 __attribute__((ext_vector_type(4)));
typedef __bf16 bf16x8 __attribute__((ext_vector_type(8)));
typedef float  f32x4  __attribute__((ext_vector_type(4)));

__device__ __forceinline__ float b2f(bf16 x) { return __bfloat162float(x); }
__device__ __forceinline__ bf16 f2b(float x) { return __float2bfloat16(x); }

// ---------------------------------------------------------------------------
// K1: LN1 + QKV projection. 16 rows/block, 256 threads. q/k/v out in fp16.
// ---------------------------------------------------------------------------
__global__ __launch_bounds__(256) void k_ln_qkv(
    const float* __restrict__ x, const float* __restrict__ g1, const float* __restrict__ b1,
    const float* __restrict__ wq, const float* __restrict__ bq,
    const float* __restrict__ wk, const float* __restrict__ bk,
    const float* __restrict__ wv, const float* __restrict__ bv,
    f16* __restrict__ qo, f16* __restrict__ ko, f16* __restrict__ vo)
{
    __shared__ float xn[16 * D_];
    const int tid = threadIdx.x;
    const int wave = tid >> 6, lane = tid & 63;
    const int rowbase = blockIdx.x * 16;

    #pragma unroll
    for (int i = 0; i < 4; ++i) {
        const int r = wave * 4 + i;
        const float* xp = x + (size_t)(rowbase + r) * D_;
        const float x0 = xp[lane];
        const float x1 = xp[lane + 64];
        const float x2 = xp[lane + 128];
        float s = x0 + x1 + x2;
        float q = x0 * x0 + x1 * x1 + x2 * x2;
        #pragma unroll
        for (int m = 1; m < 64; m <<= 1) {
            s += __shfl_xor(s, m, 64);
            q += __shfl_xor(q, m, 64);
        }
        const float mean = s * (1.0f / 192.0f);
        const float var  = q * (1.0f / 192.0f) - mean * mean;
        const float rs   = rsqrtf(var + EPS_);
        xn[r * D_ + lane]       = (x0 - mean) * rs * g1[lane]       + b1[lane];
        xn[r * D_ + lane + 64]  = (x1 - mean) * rs * g1[lane + 64]  + b1[lane + 64];
        xn[r * D_ + lane + 128] = (x2 - mean) * rs * g1[lane + 128] + b1[lane + 128];
    }
    __syncthreads();

    if (tid < 144) {
        const int sel = tid / 48, col = tid % 48;
        const float* W  = sel == 0 ? wq : (sel == 1 ? wk : wv);
        const float* Bp = sel == 0 ? bq : (sel == 1 ? bk : bv);
        f16* O          = sel == 0 ? qo : (sel == 1 ? ko : vo);
        float acc[16];
        #pragma unroll
        for (int r = 0; r < 16; ++r) acc[r] = 0.f;
        for (int c = 0; c < D_; c += 4) {
            const float w0 = W[(c + 0) * HK_ + col];
            const float w1 = W[(c + 1) * HK_ + col];
            const float w2 = W[(c + 2) * HK_ + col];
            const float w3 = W[(c + 3) * HK_ + col];
            #pragma unroll
            for (int r = 0; r < 16; ++r) {
                const float4 xv = *(const float4*)&xn[r * D_ + c];
                acc[r] = fmaf(xv.x, w0, fmaf(xv.y, w1, fmaf(xv.z, w2, fmaf(xv.w, w3, acc[r]))));
            }
        }
        const float bb = Bp[col];
        #pragma unroll
        for (int r = 0; r < 16; ++r)
            O[(size_t)(rowbase + r) * HK_ + col] = (f16)(acc[r] + bb);
    }
}

// ---------------------------------------------------------------------------
// K2a: MFMA attention partials. Block = (bh, qt, ks) 256q x 256k causal tile
// pair (2304 blocks), 256 threads. Wave w: queries qt*256+w*64..+63, all keys
// of the slab. Zero LDS.
//   S^T = K . Q^T  via v_mfma_f32_16x16x16_f16 (hd 12 padded to 16, quad-3
//   lanes zeroed).  S^T C-frag = [key=quad*4+reg][q=lane&15]  ==  A-operand
//   layout A[m=q][k=key] of the PV MFMA -> exp/mask in-register, feed P
//   directly into O += P.V (V B-frags prepacked from global).
// Fixed-shift softmax p=exp(s*scale-6): partials combine by plain addition.
// ---------------------------------------------------------------------------
__global__ __launch_bounds__(256) void k_attn_part(
    const f16* __restrict__ qh, const f16* __restrict__ kh, const f16* __restrict__ vh,
    bf16* __restrict__ part_o, float* __restrict__ part_l)
{
    const int tid = threadIdx.x;
    const int wv = tid >> 6, lane = tid & 63;
    const int quad = lane >> 4, l15 = lane & 15;
    const int bh = blockIdx.x / 36;
    int r = blockIdx.x % 36;
    int qt = 0;
    while (r >= qt + 1) { r -= qt + 1; ++qt; }
    const int ks = r;
    const int b = bh >> 2, h = bh & 3;
    const size_t base = (size_t)b * L_ * HK_ + h * 12;
    const int kbase = ks * 256;
    const int qbase = qt * 256 + wv * 64;
    const int ktmax = (ks == qt) ? 4 * (wv + 1) : 16;

    // Q^T B-frags: B[k=hd=quad*4+j][n=q=l15]; quad3 (hd 12..15) zeroed.
    f16x4 Qf[4];
    #pragma unroll
    for (int s = 0; s < 4; ++s) {
        f16x4 v; v[0] = 0; v[1] = 0; v[2] = 0; v[3] = 0;
        if (quad < 3) {
            const f16* qp = qh + base + (size_t)(qbase + s * 16 + l15) * HK_ + quad * 4;
            v[0] = qp[0]; v[1] = qp[1]; v[2] = qp[2]; v[3] = qp[3];
        }
        Qf[s] = v;
    }
    // K A-frags: A[m=key=l15][k=hd=quad*4+j]; V B-frags: B[k=key=quad*4+j][n=vcol=l15]
    f16x4 Kf[16], Vf[16];
    #pragma unroll
    for (int kt = 0; kt < 16; ++kt) {
        f16x4 kv; kv[0] = 0; kv[1] = 0; kv[2] = 0; kv[3] = 0;
        f16x4 vvv; vvv[0] = 0; vvv[1] = 0; vvv[2] = 0; vvv[3] = 0;
        if (kt < ktmax) {
            if (quad < 3) {
                const f16* kp = kh + base + (size_t)(kbase + kt * 16 + l15) * HK_ + quad * 4;
                kv[0] = kp[0]; kv[1] = kp[1]; kv[2] = kp[2]; kv[3] = kp[3];
            }
            const f16* vp = vh + base;
            const int k0 = kbase + kt * 16 + quad * 4;
            vvv[0] = vp[(size_t)(k0 + 0) * HK_ + l15];
            vvv[1] = vp[(size_t)(k0 + 1) * HK_ + l15];
            vvv[2] = vp[(size_t)(k0 + 2) * HK_ + l15];
            vvv[3] = vp[(size_t)(k0 + 3) * HK_ + l15];
        }
        Kf[kt] = kv; Vf[kt] = vvv;
    }

    f32x4 O[4];
    float lacc[4];
    #pragma unroll
    for (int s = 0; s < 4; ++s) { O[s] = (f32x4){0.f, 0.f, 0.f, 0.f}; lacc[s] = 0.f; }

    for (int kt = 0; kt < ktmax; ++kt) {
        const int k0 = kbase + kt * 16 + quad * 4;
        #pragma unroll
        for (int s = 0; s < 4; ++s) {
            f32x4 sc = (f32x4){0.f, 0.f, 0.f, 0.f};
            sc = __builtin_amdgcn_mfma_f32_16x16x16f16(Kf[kt], Qf[s], sc, 0, 0, 0);
            const int qg = qbase + s * 16 + l15;
            f16x4 p;
            #pragma unroll
            for (int j = 0; j < 4; ++j) {
                float pv = __expf(fmaf(sc[j], SCALE_, -6.0f));
                pv = (k0 + j <= qg) ? pv : 0.f;
                lacc[s] += pv;
                p[j] = (f16)pv;
            }
            O[s] = __builtin_amdgcn_mfma_f32_16x16x16f16(p, Vf[kt], O[s], 0, 0, 0);
        }
    }

    // reduce l across the 4 quads (keys axis), then write partials
    #pragma unroll
    for (int s = 0; s < 4; ++s) {
        float l = lacc[s];
        l += __shfl_xor(l, 16, 64);
        l += __shfl_xor(l, 32, 64);
        lacc[s] = l;
    }
    #pragma unroll
    for (int s = 0; s < 4; ++s) {
        const int q16 = qbase + s * 16;
        if (quad == 0)
            part_l[((size_t)bh * L_ + q16 + l15) * 8 + ks] = lacc[s];
        if (l15 < 12) {
            #pragma unroll
            for (int j = 0; j < 4; ++j) {
                const int qq = q16 + quad * 4 + j;
                part_o[(((size_t)bh * L_ + qq) * 8 + ks) * 12 + l15] = f2b(O[s][j]);
            }
        }
    }
}

// ---------------------------------------------------------------------------
// K2b: combine partials -> ctx (bf16).
// ---------------------------------------------------------------------------
__global__ __launch_bounds__(256) void k_attn_comb(
    const bf16* __restrict__ part_o, const float* __restrict__ part_l,
    bf16* __restrict__ ctx)
{
    const int idx = blockIdx.x * 256 + threadIdx.x;   // bh*L + q
    const int bh = idx >> 11, q = idx & 2047;
    const int b = bh >> 2, h = bh & 3;
    const int ns = (q >> 8) + 1;
    const bf16* op = part_o + (size_t)idx * 96;
    const float* lp = part_l + (size_t)idx * 8;
    float l = 0.f, o[12];
    #pragma unroll
    for (int i = 0; i < 12; ++i) o[i] = 0.f;
    for (int s = 0; s < ns; ++s) {
        l += lp[s];
        #pragma unroll
        for (int i = 0; i < 12; ++i) o[i] += b2f(op[s * 12 + i]);
    }
    const float inv = 1.0f / l;
    bf16* cp = ctx + ((size_t)b * L_ + q) * HK_ + h * 12;
    #pragma unroll
    for (int i = 0; i < 12; ++i) cp[i] = f2b(o[i] * inv);
}

// ---------------------------------------------------------------------------
// K3: out-proj + residual + LN2 -> x2 (fp32) + xn2b (bf16).
// ---------------------------------------------------------------------------
__global__ __launch_bounds__(192) void k_proj_ln2(
    const float* __restrict__ x, const bf16* __restrict__ ctx,
    const float* __restrict__ wo, const float* __restrict__ bo,
    const float* __restrict__ g2, const float* __restrict__ lb2,
    float* __restrict__ x2, bf16* __restrict__ xn2b)
{
    __shared__ float cl[8 * HK_];
    __shared__ float x2l[8 * D_];
    const int tid = threadIdx.x;
    const int rowbase = blockIdx.x * 8;
    cl[tid]       = b2f(ctx[(size_t)rowbase * HK_ + tid]);
    cl[tid + 192] = b2f(ctx[(size_t)rowbase * HK_ + tid + 192]);
    __syncthreads();

    const int d = tid;
    float acc[8];
    #pragma unroll
    for (int r = 0; r < 8; ++r) acc[r] = 0.f;
    for (int j = 0; j < HK_; j += 4) {
        const float w0 = wo[(j + 0) * D_ + d];
        const float w1 = wo[(j + 1) * D_ + d];
        const float w2 = wo[(j + 2) * D_ + d];
        const float w3 = wo[(j + 3) * D_ + d];
        #pragma unroll
        for (int r = 0; r < 8; ++r) {
            const float4 cv = *(const float4*)&cl[r * HK_ + j];
            acc[r] = fmaf(cv.x, w0, fmaf(cv.y, w1, fmaf(cv.z, w2, fmaf(cv.w, w3, acc[r]))));
        }
    }
    const float bod = bo[d];
    #pragma unroll
    for (int r = 0; r < 8; ++r) {
        const size_t idx = (size_t)(rowbase + r) * D_ + d;
        const float v = acc[r] + bod + x[idx];
        x2[idx] = v;
        x2l[r * D_ + d] = v;
    }
    __syncthreads();

    const int wave = tid >> 6, lane = tid & 63;
    for (int r = wave; r < 8; r += 3) {
        const float x0  = x2l[r * D_ + lane];
        const float x1  = x2l[r * D_ + lane + 64];
        const float xv2 = x2l[r * D_ + lane + 128];
        float s = x0 + x1 + xv2;
        float q = x0 * x0 + x1 * x1 + xv2 * xv2;
        #pragma unroll
        for (int m = 1; m < 64; m <<= 1) {
            s += __shfl_xor(s, m, 64);
            q += __shfl_xor(q, m, 64);
        }
        const float mean = s * (1.0f / 192.0f);
        const float var  = q * (1.0f / 192.0f) - mean * mean;
        const float rs   = rsqrtf(var + EPS_);
        const size_t ro = (size_t)(rowbase + r) * D_;
        xn2b[ro + lane]       = f2b((x0 - mean) * rs * g2[lane]       + lb2[lane]);
        xn2b[ro + lane + 64]  = f2b((x1 - mean) * rs * g2[lane + 64]  + lb2[lane + 64]);
        xn2b[ro + lane + 128] = f2b((xv2 - mean) * rs * g2[lane + 128] + lb2[lane + 128]);
    }
}

// ---------------------------------------------------------------------------
// K-prep: repack conv weight [576][192] fp32 -> bf16 W'[kb][n][kk], kk=k%32.
// ---------------------------------------------------------------------------
__global__ __launch_bounds__(256) void k_wprep(
    const float* __restrict__ w, bf16* __restrict__ wr)
{
    const int i = blockIdx.x * 256 + threadIdx.x;   // i = k*192 + n
    if (i < 576 * 192) {
        const int k = i / 192, n = i - k * 192;
        wr[((size_t)(k >> 5) * 192 + n) * 32 + (k & 31)] = f2b(w[i]);
    }
}

// ---------------------------------------------------------------------------
// K4/K5: conv as MFMA GEMM (unchanged from round 5).
// ---------------------------------------------------------------------------
template <int IS_CONV1>
__global__ __launch_bounds__(256) void k_conv_mfma(
    const bf16* __restrict__ act, const bf16* __restrict__ wrep,
    const float* __restrict__ bias, const float* __restrict__ x2,
    bf16* __restrict__ outb, float* __restrict__ outf)
{
    const int wave = threadIdx.x >> 6, lane = threadIdx.x & 63;
    const int m16 = lane & 15, q = lane >> 4;
    const int rowbase = blockIdx.x * 64 + wave * 16;

    f32x4 acc[12];
    #pragma unroll
    for (int nt = 0; nt < 12; ++nt) acc[nt] = (f32x4){0.f, 0.f, 0.f, 0.f};

    #pragma unroll
    for (int t = 0; t < 3; ++t) {
        const long long arow = (long long)rowbase + m16 + t - 1;
        const bf16* ap = act + arow * D_ + q * 8;
        #pragma unroll
        for (int c6 = 0; c6 < 6; ++c6) {
            const int kb = t * 6 + c6;
            const bf16x8 a = *(const bf16x8*)(ap + c6 * 32);
            const bf16* wp = wrep + ((size_t)kb * 192 + m16) * 32 + q * 8;
            #pragma unroll
            for (int nt = 0; nt < 12; ++nt) {
                const bf16x8 b = *(const bf16x8*)(wp + (size_t)nt * 16 * 32);
                acc[nt] = __builtin_amdgcn_mfma_f32_16x16x32_bf16(a, b, acc[nt], 0, 0, 0);
            }
        }
    }

    #pragma unroll
    for (int nt = 0; nt < 12; ++nt) {
        const int col = nt * 16 + m16;
        const float bd = bias[col];
        #pragma unroll
        for (int reg = 0; reg < 4; ++reg) {
            const int r = rowbase + q * 4 + reg;
            const int m = r & (L_ - 1);
            const size_t idx = (size_t)r * D_ + col;
            if (IS_CONV1) {
                float v = fmaxf(acc[nt][reg] + bd, 0.f);
                if (m == 0 || m == L_ - 1) v = 0.f;
                outb[idx] = f2b(v);
            } else {
                float v = x2[idx];
                if (m != 0 && m != L_ - 1) v += acc[nt][reg] + bd;
                outf[idx] = v;
            }
        }
    }
}

// ---------------------------------------------------------------------------
extern "C" void kernel_launch(void* const* d_in, const int* in_sizes, int n_in,
                              void* d_out, int out_size, void* d_ws, size_t ws_size,
                              hipStream_t stream)
{
    const float* x    = (const float*)d_in[0];
    const float* ln1g = (const float*)d_in[1];
    const float* ln1b = (const float*)d_in[2];
    const float* wq   = (const float*)d_in[3];
    const float* bq   = (const float*)d_in[4];
    const float* wk   = (const float*)d_in[5];
    const float* bk   = (const float*)d_in[6];
    const float* wv   = (const float*)d_in[7];
    const float* bv   = (const float*)d_in[8];
    const float* wo   = (const float*)d_in[9];
    const float* bo   = (const float*)d_in[10];
    const float* ln2g = (const float*)d_in[11];
    const float* ln2b = (const float*)d_in[12];
    const float* c1w  = (const float*)d_in[13];
    const float* c1b  = (const float*)d_in[14];
    const float* c2w  = (const float*)d_in[15];
    const float* c2b  = (const float*)d_in[16];

    const size_t ROWS = (size_t)16 * L_;            // 32768
    char* ws = (char*)d_ws;
    size_t off = 4096;                               // guard (conv row -1)
    bf16* xn2b = (bf16*)(ws + off); off += ROWS * D_ * 2;    // 12.6 MB
    off += 4096;                                     // guard
    bf16* hpb  = (bf16*)(ws + off); off += ROWS * D_ * 2;    // 12.6 MB
    off += 4096;                                     // guard
    float* x2  = (float*)(ws + off); off += ROWS * D_ * 4;   // 25.2 MB
    f16* qb    = (f16*)(ws + off);   off += ROWS * HK_ * 2;  // 3.15 MB
    f16* kb    = (f16*)(ws + off);   off += ROWS * HK_ * 2;
    f16* vb2   = (f16*)(ws + off);   off += ROWS * HK_ * 2;
    bf16* ctx  = (bf16*)(ws + off);  off += ROWS * HK_ * 2;
    bf16* wrep1 = (bf16*)(ws + off); off += 576 * 192 * 2;   // 221 KB
    bf16* wrep2 = (bf16*)(ws + off); off += 576 * 192 * 2;   // total ~64 MB

    // attention partials ALIAS later-written buffers (consumed by attn_comb
    // before proj_ln2 writes x2 / conv1 writes hpb):
    bf16*  part_o = (bf16*)x2;       // 25.17 MB (exactly fits x2 region)
    float* part_l = (float*)hpb;     //  4.2 MB

    k_wprep        <<<432, 256, 0, stream>>>(c1w, wrep1);
    k_wprep        <<<432, 256, 0, stream>>>(c2w, wrep2);
    k_ln_qkv       <<<2048, 256, 0, stream>>>(x, ln1g, ln1b, wq, bq, wk, bk, wv, bv, qb, kb, vb2);
    k_attn_part    <<<64 * 36, 256, 0, stream>>>(qb, kb, vb2, part_o, part_l);
    k_attn_comb    <<< 512, 256, 0, stream>>>(part_o, part_l, ctx);
    k_proj_ln2     <<<4096, 192, 0, stream>>>(x, ctx, wo, bo, ln2g, ln2b, x2, xn2b);
    k_conv_mfma<1> <<< 512, 256, 0, stream>>>(xn2b, wrep1, c1b, nullptr, hpb, nullptr);
    k_conv_mfma<0> <<< 512, 256, 0, stream>>>(hpb, wrep2, c2b, x2, nullptr, (float*)d_out);
}

// Round 7
// 292.717 us; speedup vs baseline: 2.2269x; 2.2269x over previous
//
#include <hip/hip_runtime.h>
#include <hip/hip_bf16.h>

#define L_ 2048
#define D_ 192
#define HK_ 48
#define EPS_ 1e-3f
#define SCALE_ 0.28867513459481287f  // 1/sqrt(12)

typedef __hip_bfloat16 bf16;
typedef _Float16 f16;
typedef _Float16 f16x4 __attribute__((ext_vector_type(4)));
typedef __bf16 bf16x8 __attribute__((ext_vector_type(8)));
typedef float  f32x4  __attribute__((ext_vector_type(4)));

__device__ __forceinline__ float b2f(bf16 x) { return __bfloat162float(x); }
__device__ __forceinline__ bf16 f2b(float x) { return __float2bfloat16(x); }

// ---------------------------------------------------------------------------
// K1: LN1 + QKV projection. 16 rows/block, 256 threads.
// q: fp16, pre-scaled by 1/sqrt(K).  k: fp16 row-major.
// v: fp16 TRANSPOSED layout vt[(bh*16 + vcol)*2048 + pos]; vcol 12 = 1.0
// (ones column -> PV MFMA col 12 yields the softmax denominator l), 13-15 = 0.
// ---------------------------------------------------------------------------
__global__ __launch_bounds__(256) void k_ln_qkv(
    const float* __restrict__ x, const float* __restrict__ g1, const float* __restrict__ b1,
    const float* __restrict__ wq, const float* __restrict__ bq,
    const float* __restrict__ wk, const float* __restrict__ bk,
    const float* __restrict__ wv, const float* __restrict__ bv,
    f16* __restrict__ qo, f16* __restrict__ ko, f16* __restrict__ vt)
{
    __shared__ float xn[16 * D_];
    const int tid = threadIdx.x;
    const int wave = tid >> 6, lane = tid & 63;
    const int rowbase = blockIdx.x * 16;

    #pragma unroll
    for (int i = 0; i < 4; ++i) {
        const int r = wave * 4 + i;
        const float* xp = x + (size_t)(rowbase + r) * D_;
        const float x0 = xp[lane];
        const float x1 = xp[lane + 64];
        const float x2 = xp[lane + 128];
        float s = x0 + x1 + x2;
        float q = x0 * x0 + x1 * x1 + x2 * x2;
        #pragma unroll
        for (int m = 1; m < 64; m <<= 1) {
            s += __shfl_xor(s, m, 64);
            q += __shfl_xor(q, m, 64);
        }
        const float mean = s * (1.0f / 192.0f);
        const float var  = q * (1.0f / 192.0f) - mean * mean;
        const float rs   = rsqrtf(var + EPS_);
        xn[r * D_ + lane]       = (x0 - mean) * rs * g1[lane]       + b1[lane];
        xn[r * D_ + lane + 64]  = (x1 - mean) * rs * g1[lane + 64]  + b1[lane + 64];
        xn[r * D_ + lane + 128] = (x2 - mean) * rs * g1[lane + 128] + b1[lane + 128];
    }
    __syncthreads();

    // ones/zeros columns of vt (vcol 12..15) for this block's 16 positions
    {
        const int h  = tid >> 6;
        const int vc = 12 + ((tid >> 4) & 3);
        const int row = rowbase + (tid & 15);
        const int b = row >> 11, lrow = row & 2047;
        vt[((size_t)(b * 4 + h) * 16 + vc) * 2048 + lrow] = (vc == 12) ? (f16)1.0f : (f16)0.0f;
    }

    if (tid < 144) {
        const int sel = tid / 48, col = tid % 48;
        const float* W  = sel == 0 ? wq : (sel == 1 ? wk : wv);
        const float* Bp = sel == 0 ? bq : (sel == 1 ? bk : bv);
        float acc[16];
        #pragma unroll
        for (int r = 0; r < 16; ++r) acc[r] = 0.f;
        for (int c = 0; c < D_; c += 4) {
            const float w0 = W[(c + 0) * HK_ + col];
            const float w1 = W[(c + 1) * HK_ + col];
            const float w2 = W[(c + 2) * HK_ + col];
            const float w3 = W[(c + 3) * HK_ + col];
            #pragma unroll
            for (int r = 0; r < 16; ++r) {
                const float4 xv = *(const float4*)&xn[r * D_ + c];
                acc[r] = fmaf(xv.x, w0, fmaf(xv.y, w1, fmaf(xv.z, w2, fmaf(xv.w, w3, acc[r]))));
            }
        }
        const float bb = Bp[col];
        if (sel == 0) {
            #pragma unroll
            for (int r = 0; r < 16; ++r)
                qo[(size_t)(rowbase + r) * HK_ + col] = (f16)((acc[r] + bb) * SCALE_);
        } else if (sel == 1) {
            #pragma unroll
            for (int r = 0; r < 16; ++r)
                ko[(size_t)(rowbase + r) * HK_ + col] = (f16)(acc[r] + bb);
        } else {
            const int h = col / 12, c12 = col % 12;
            #pragma unroll
            for (int r = 0; r < 16; ++r) {
                const int row = rowbase + r;
                const int b = row >> 11, lrow = row & 2047;
                vt[((size_t)(b * 4 + h) * 16 + c12) * 2048 + lrow] = (f16)(acc[r] + bb);
            }
        }
    }
}

// ---------------------------------------------------------------------------
// K2a: MFMA attention partials. Block = (bh, qt, ks) 256q x 256k causal tile
// pair (2304 blocks), 256 threads, zero LDS, no fragment arrays (anti-spill).
//   S^T = K . Q^T (hd 12->16 padded, quad-3 zeroed).  S^T C-frag ==
//   A-operand layout of the PV MFMA; exp in-register; V B-frag is one 8-B
//   load from transposed vt.  vt col 12 == 1.0 -> O[.][12] = l.
// Off-diagonal tiles: no causal mask at all (loop bounds guarantee k < q).
// ---------------------------------------------------------------------------
__global__ __launch_bounds__(256) void k_attn_part(
    const f16* __restrict__ qh, const f16* __restrict__ kh, const f16* __restrict__ vt,
    bf16* __restrict__ part_o, float* __restrict__ part_l)
{
    const int tid = threadIdx.x;
    const int wv = tid >> 6, lane = tid & 63;
    const int quad = lane >> 4, l15 = lane & 15;
    const int bh = blockIdx.x / 36;
    int r = blockIdx.x % 36;
    int qt = 0;
    while (r >= qt + 1) { r -= qt + 1; ++qt; }
    const int ks = r;
    const int b = bh >> 2, h = bh & 3;
    const size_t base  = (size_t)b * L_ * HK_ + h * 12;
    const size_t vbase = ((size_t)bh * 16 + l15) * 2048;
    const int kbase = ks * 256;
    const int qbase = qt * 256 + wv * 64;
    const bool diag = (ks == qt);
    const int ktmax = diag ? 4 * (wv + 1) : 16;

    // Q^T B-frags: B[k=hd=quad*4+j][n=q=l15]; quad3 (hd 12..15) zeroed.
    f16x4 Qf[4];
    #pragma unroll
    for (int s = 0; s < 4; ++s) {
        f16x4 v; v[0] = 0; v[1] = 0; v[2] = 0; v[3] = 0;
        if (quad < 3)
            v = *(const f16x4*)(qh + base + (size_t)(qbase + s * 16 + l15) * HK_ + quad * 4);
        Qf[s] = v;
    }

    f32x4 O[4];
    #pragma unroll
    for (int s = 0; s < 4; ++s) O[s] = (f32x4){0.f, 0.f, 0.f, 0.f};

    for (int kt = 0; kt < ktmax; ++kt) {
        const int k0 = kbase + kt * 16 + quad * 4;
        f16x4 Kf; Kf[0] = 0; Kf[1] = 0; Kf[2] = 0; Kf[3] = 0;
        if (quad < 3)
            Kf = *(const f16x4*)(kh + base + (size_t)(kbase + kt * 16 + l15) * HK_ + quad * 4);
        const f16x4 Vf = *(const f16x4*)(vt + vbase + k0);
        #pragma unroll
        for (int s = 0; s < 4; ++s) {
            f32x4 sc = (f32x4){0.f, 0.f, 0.f, 0.f};
            sc = __builtin_amdgcn_mfma_f32_16x16x16f16(Kf, Qf[s], sc, 0, 0, 0);
            f16x4 p;
            if (diag) {
                const int qg = qbase + s * 16 + l15;
                #pragma unroll
                for (int j = 0; j < 4; ++j) {
                    float pv = __expf(sc[j] - 6.0f);
                    p[j] = (f16)((k0 + j <= qg) ? pv : 0.f);
                }
            } else {
                #pragma unroll
                for (int j = 0; j < 4; ++j)
                    p[j] = (f16)__expf(sc[j] - 6.0f);
            }
            O[s] = __builtin_amdgcn_mfma_f32_16x16x16f16(p, Vf, O[s], 0, 0, 0);
        }
    }

    #pragma unroll
    for (int s = 0; s < 4; ++s) {
        const int q16 = qbase + s * 16;
        #pragma unroll
        for (int j = 0; j < 4; ++j) {
            const int qq = q16 + quad * 4 + j;
            const size_t slot = ((size_t)bh * L_ + qq) * 8 + ks;
            if (l15 < 12)       part_o[slot * 12 + l15] = f2b(O[s][j]);
            else if (l15 == 12) part_l[slot] = O[s][j];
        }
    }
}

// ---------------------------------------------------------------------------
// K2b: combine partials -> ctx (bf16).
// ---------------------------------------------------------------------------
__global__ __launch_bounds__(256) void k_attn_comb(
    const bf16* __restrict__ part_o, const float* __restrict__ part_l,
    bf16* __restrict__ ctx)
{
    const int idx = blockIdx.x * 256 + threadIdx.x;   // bh*L + q
    const int bh = idx >> 11, q = idx & 2047;
    const int b = bh >> 2, h = bh & 3;
    const int ns = (q >> 8) + 1;
    const bf16* op = part_o + (size_t)idx * 96;
    const float* lp = part_l + (size_t)idx * 8;
    float l = 0.f, o[12];
    #pragma unroll
    for (int i = 0; i < 12; ++i) o[i] = 0.f;
    for (int s = 0; s < ns; ++s) {
        l += lp[s];
        #pragma unroll
        for (int i = 0; i < 12; ++i) o[i] += b2f(op[s * 12 + i]);
    }
    const float inv = 1.0f / l;
    bf16* cp = ctx + ((size_t)b * L_ + q) * HK_ + h * 12;
    #pragma unroll
    for (int i = 0; i < 12; ++i) cp[i] = f2b(o[i] * inv);
}

// ---------------------------------------------------------------------------
// K3: out-proj + residual + LN2 -> x2 (fp32) + xn2b (bf16).
// ---------------------------------------------------------------------------
__global__ __launch_bounds__(192) void k_proj_ln2(
    const float* __restrict__ x, const bf16* __restrict__ ctx,
    const float* __restrict__ wo, const float* __restrict__ bo,
    const float* __restrict__ g2, const float* __restrict__ lb2,
    float* __restrict__ x2, bf16* __restrict__ xn2b)
{
    __shared__ float cl[8 * HK_];
    __shared__ float x2l[8 * D_];
    const int tid = threadIdx.x;
    const int rowbase = blockIdx.x * 8;
    cl[tid]       = b2f(ctx[(size_t)rowbase * HK_ + tid]);
    cl[tid + 192] = b2f(ctx[(size_t)rowbase * HK_ + tid + 192]);
    __syncthreads();

    const int d = tid;
    float acc[8];
    #pragma unroll
    for (int r = 0; r < 8; ++r) acc[r] = 0.f;
    for (int j = 0; j < HK_; j += 4) {
        const float w0 = wo[(j + 0) * D_ + d];
        const float w1 = wo[(j + 1) * D_ + d];
        const float w2 = wo[(j + 2) * D_ + d];
        const float w3 = wo[(j + 3) * D_ + d];
        #pragma unroll
        for (int r = 0; r < 8; ++r) {
            const float4 cv = *(const float4*)&cl[r * HK_ + j];
            acc[r] = fmaf(cv.x, w0, fmaf(cv.y, w1, fmaf(cv.z, w2, fmaf(cv.w, w3, acc[r]))));
        }
    }
    const float bod = bo[d];
    #pragma unroll
    for (int r = 0; r < 8; ++r) {
        const size_t idx = (size_t)(rowbase + r) * D_ + d;
        const float v = acc[r] + bod + x[idx];
        x2[idx] = v;
        x2l[r * D_ + d] = v;
    }
    __syncthreads();

    const int wave = tid >> 6, lane = tid & 63;
    for (int r = wave; r < 8; r += 3) {
        const float x0  = x2l[r * D_ + lane];
        const float x1  = x2l[r * D_ + lane + 64];
        const float xv2 = x2l[r * D_ + lane + 128];
        float s = x0 + x1 + xv2;
        float q = x0 * x0 + x1 * x1 + xv2 * xv2;
        #pragma unroll
        for (int m = 1; m < 64; m <<= 1) {
            s += __shfl_xor(s, m, 64);
            q += __shfl_xor(q, m, 64);
        }
        const float mean = s * (1.0f / 192.0f);
        const float var  = q * (1.0f / 192.0f) - mean * mean;
        const float rs   = rsqrtf(var + EPS_);
        const size_t ro = (size_t)(rowbase + r) * D_;
        xn2b[ro + lane]       = f2b((x0 - mean) * rs * g2[lane]       + lb2[lane]);
        xn2b[ro + lane + 64]  = f2b((x1 - mean) * rs * g2[lane + 64]  + lb2[lane + 64]);
        xn2b[ro + lane + 128] = f2b((xv2 - mean) * rs * g2[lane + 128] + lb2[lane + 128]);
    }
}

// ---------------------------------------------------------------------------
// K-prep: repack conv weight [576][192] fp32 -> bf16 W'[kb][n][kk], kk=k%32.
// ---------------------------------------------------------------------------
__global__ __launch_bounds__(256) void k_wprep(
    const float* __restrict__ w, bf16* __restrict__ wr)
{
    const int i = blockIdx.x * 256 + threadIdx.x;   // i = k*192 + n
    if (i < 576 * 192) {
        const int k = i / 192, n = i - k * 192;
        wr[((size_t)(k >> 5) * 192 + n) * 32 + (k & 31)] = f2b(w[i]);
    }
}

// ---------------------------------------------------------------------------
// K4/K5: conv as MFMA GEMM (unchanged).
// ---------------------------------------------------------------------------
template <int IS_CONV1>
__global__ __launch_bounds__(256) void k_conv_mfma(
    const bf16* __restrict__ act, const bf16* __restrict__ wrep,
    const float* __restrict__ bias, const float* __restrict__ x2,
    bf16* __restrict__ outb, float* __restrict__ outf)
{
    const int wave = threadIdx.x >> 6, lane = threadIdx.x & 63;
    const int m16 = lane & 15, q = lane >> 4;
    const int rowbase = blockIdx.x * 64 + wave * 16;

    f32x4 acc[12];
    #pragma unroll
    for (int nt = 0; nt < 12; ++nt) acc[nt] = (f32x4){0.f, 0.f, 0.f, 0.f};

    #pragma unroll
    for (int t = 0; t < 3; ++t) {
        const long long arow = (long long)rowbase + m16 + t - 1;
        const bf16* ap = act + arow * D_ + q * 8;
        #pragma unroll
        for (int c6 = 0; c6 < 6; ++c6) {
            const int kb = t * 6 + c6;
            const bf16x8 a = *(const bf16x8*)(ap + c6 * 32);
            const bf16* wp = wrep + ((size_t)kb * 192 + m16) * 32 + q * 8;
            #pragma unroll
            for (int nt = 0; nt < 12; ++nt) {
                const bf16x8 b = *(const bf16x8*)(wp + (size_t)nt * 16 * 32);
                acc[nt] = __builtin_amdgcn_mfma_f32_16x16x32_bf16(a, b, acc[nt], 0, 0, 0);
            }
        }
    }

    #pragma unroll
    for (int nt = 0; nt < 12; ++nt) {
        const int col = nt * 16 + m16;
        const float bd = bias[col];
        #pragma unroll
        for (int reg = 0; reg < 4; ++reg) {
            const int r = rowbase + q * 4 + reg;
            const int m = r & (L_ - 1);
            const size_t idx = (size_t)r * D_ + col;
            if (IS_CONV1) {
                float v = fmaxf(acc[nt][reg] + bd, 0.f);
                if (m == 0 || m == L_ - 1) v = 0.f;
                outb[idx] = f2b(v);
            } else {
                float v = x2[idx];
                if (m != 0 && m != L_ - 1) v += acc[nt][reg] + bd;
                outf[idx] = v;
            }
        }
    }
}

// ---------------------------------------------------------------------------
extern "C" void kernel_launch(void* const* d_in, const int* in_sizes, int n_in,
                              void* d_out, int out_size, void* d_ws, size_t ws_size,
                              hipStream_t stream)
{
    const float* x    = (const float*)d_in[0];
    const float* ln1g = (const float*)d_in[1];
    const float* ln1b = (const float*)d_in[2];
    const float* wq   = (const float*)d_in[3];
    const float* bq   = (const float*)d_in[4];
    const float* wk   = (const float*)d_in[5];
    const float* bk   = (const float*)d_in[6];
    const float* wv   = (const float*)d_in[7];
    const float* bv   = (const float*)d_in[8];
    const float* wo   = (const float*)d_in[9];
    const float* bo   = (const float*)d_in[10];
    const float* ln2g = (const float*)d_in[11];
    const float* ln2b = (const float*)d_in[12];
    const float* c1w  = (const float*)d_in[13];
    const float* c1b  = (const float*)d_in[14];
    const float* c2w  = (const float*)d_in[15];
    const float* c2b  = (const float*)d_in[16];

    const size_t ROWS = (size_t)16 * L_;            // 32768
    char* ws = (char*)d_ws;
    size_t off = 4096;                               // guard (conv row -1)
    bf16* xn2b = (bf16*)(ws + off); off += ROWS * D_ * 2;    // 12.6 MB
    off += 4096;                                     // guard
    bf16* hpb  = (bf16*)(ws + off); off += ROWS * D_ * 2;    // 12.6 MB
    off += 4096;                                     // guard
    float* x2  = (float*)(ws + off); off += ROWS * D_ * 4;   // 25.2 MB
    f16* qb    = (f16*)(ws + off);   off += ROWS * HK_ * 2;  // 3.15 MB
    f16* kb    = (f16*)(ws + off);   off += ROWS * HK_ * 2;
    f16* vt    = (f16*)(ws + off);   off += (size_t)64 * 16 * 2048 * 2;  // 4.19 MB
    bf16* ctx  = (bf16*)(ws + off);  off += ROWS * HK_ * 2;
    bf16* wrep1 = (bf16*)(ws + off); off += 576 * 192 * 2;   // 221 KB
    bf16* wrep2 = (bf16*)(ws + off); off += 576 * 192 * 2;   // total ~66 MB

    // attention partials ALIAS later-written buffers (consumed by attn_comb
    // before proj_ln2 writes x2 / conv1 writes hpb):
    bf16*  part_o = (bf16*)x2;       // 25.17 MB (exactly fits x2 region)
    float* part_l = (float*)hpb;     //  4.2 MB

    k_wprep        <<<432, 256, 0, stream>>>(c1w, wrep1);
    k_wprep        <<<432, 256, 0, stream>>>(c2w, wrep2);
    k_ln_qkv       <<<2048, 256, 0, stream>>>(x, ln1g, ln1b, wq, bq, wk, bk, wv, bv, qb, kb, vt);
    k_attn_part    <<<64 * 36, 256, 0, stream>>>(qb, kb, vt, part_o, part_l);
    k_attn_comb    <<< 512, 256, 0, stream>>>(part_o, part_l, ctx);
    k_proj_ln2     <<<4096, 192, 0, stream>>>(x, ctx, wo, bo, ln2g, ln2b, x2, xn2b);
    k_conv_mfma<1> <<< 512, 256, 0, stream>>>(xn2b, wrep1, c1b, nullptr, hpb, nullptr);
    k_conv_mfma<0> <<< 512, 256, 0, stream>>>(hpb, wrep2, c2b, x2, nullptr, (float*)d_out);
}

// Round 8
// 260.075 us; speedup vs baseline: 2.5064x; 1.1255x over previous
//
#include <hip/hip_runtime.h>
#include <hip/hip_bf16.h>

#define L_ 2048
#define D_ 192
#define HK_ 48
#define EPS_ 1e-3f
#define SCALE_ 0.28867513459481287f  // 1/sqrt(12)

typedef __hip_bfloat16 bf16;
typedef _Float16 f16;
typedef _Float16 f16x4 __attribute__((ext_vector_type(4)));
typedef __bf16 bf16x8 __attribute__((ext_vector_type(8)));
typedef float  f32x4  __attribute__((ext_vector_type(4)));

__device__ __forceinline__ float b2f(bf16 x) { return __bfloat162float(x); }
__device__ __forceinline__ bf16 f2b(float x) { return __float2bfloat16(x); }

// ---------------------------------------------------------------------------
// K0a: prep combined QKV weight -> bf16 W'[kb][n][kk] (kb=k/32, kk=k%32),
// n: 0..47 = wq*SCALE, 48..95 = wk, 96..143 = wv. bias144 likewise.
// ---------------------------------------------------------------------------
__global__ __launch_bounds__(256) void k_wprep_qkv(
    const float* __restrict__ wq, const float* __restrict__ wk, const float* __restrict__ wv,
    const float* __restrict__ bq, const float* __restrict__ bk, const float* __restrict__ bv,
    bf16* __restrict__ wrep, float* __restrict__ bias144)
{
    const int i = blockIdx.x * 256 + threadIdx.x;
    if (i < 6 * 144 * 32) {
        const int kb = i / (144 * 32);
        const int rem = i % (144 * 32);
        const int n = rem / 32, kk = rem % 32;
        const int k = kb * 32 + kk;
        float v;
        if (n < 48)       v = wq[k * HK_ + n] * SCALE_;
        else if (n < 96)  v = wk[k * HK_ + (n - 48)];
        else              v = wv[k * HK_ + (n - 96)];
        wrep[((size_t)kb * 144 + n) * 32 + kk] = f2b(v);
    }
    if (i < 144) {
        bias144[i] = (i < 48) ? bq[i] * SCALE_
                   : (i < 96) ? bk[i - 48] : bv[i - 96];
    }
}

// ---------------------------------------------------------------------------
// K1: fused LN1 + QKV projection via MFMA. 64 rows/block, 256 threads.
// LN -> bf16 xn in LDS (row stride 200: 2-way bank aliasing, free).
// GEMM: M=64 (4 waves x 16), N=144 (9 n-tiles), K=192 (6 chunks of 32).
// Outputs: q fp16 (pre-scaled), k fp16 row-major; v fp16 transposed
// vt[(bh*16+vcol)*2048+pos], vcol 12 = 1.0 (gives softmax denom), 13-15 = 0.
// ---------------------------------------------------------------------------
__global__ __launch_bounds__(256) void k_ln_qkv(
    const float* __restrict__ x, const float* __restrict__ g1, const float* __restrict__ b1,
    const bf16* __restrict__ wrep, const float* __restrict__ bias144,
    f16* __restrict__ qo, f16* __restrict__ ko, f16* __restrict__ vt)
{
    __shared__ bf16 xn[64 * 200];
    const int tid = threadIdx.x;
    const int wave = tid >> 6, lane = tid & 63;
    const int rowbase = blockIdx.x * 64;
    const int b = rowbase >> 11;                 // 64 | 2048: one batch per block
    const int lrow0 = rowbase & 2047;

    const float gg0 = g1[lane], gg1 = g1[lane + 64], gg2 = g1[lane + 128];
    const float bb0 = b1[lane], bb1 = b1[lane + 64], bb2 = b1[lane + 128];
    for (int i = 0; i < 16; ++i) {
        const int r = wave * 16 + i;
        const float* xp = x + (size_t)(rowbase + r) * D_;
        const float x0 = xp[lane];
        const float x1 = xp[lane + 64];
        const float x2 = xp[lane + 128];
        float s = x0 + x1 + x2;
        float q = x0 * x0 + x1 * x1 + x2 * x2;
        #pragma unroll
        for (int m = 1; m < 64; m <<= 1) {
            s += __shfl_xor(s, m, 64);
            q += __shfl_xor(q, m, 64);
        }
        const float mean = s * (1.0f / 192.0f);
        const float var  = q * (1.0f / 192.0f) - mean * mean;
        const float rs   = rsqrtf(var + EPS_);
        xn[r * 200 + lane]       = f2b((x0 - mean) * rs * gg0 + bb0);
        xn[r * 200 + lane + 64]  = f2b((x1 - mean) * rs * gg1 + bb1);
        xn[r * 200 + lane + 128] = f2b((x2 - mean) * rs * gg2 + bb2);
    }

    // ones/zeros vt columns (vcol 12..15) for this block's 64 positions
    {
        const int h  = tid >> 6;
        const int vc = 12 + ((tid >> 4) & 3);
        const int p0 = lrow0 + (tid & 15) * 4;
        f16x4 vv;
        const f16 one = (f16)1.0f, zero = (f16)0.0f;
        vv[0] = vv[1] = vv[2] = vv[3] = (vc == 12) ? one : zero;
        *(f16x4*)(vt + ((size_t)(b * 4 + h) * 16 + vc) * 2048 + p0) = vv;
    }
    __syncthreads();

    const int l15 = lane & 15, q4 = lane >> 4;
    f32x4 acc[9];
    #pragma unroll
    for (int nt = 0; nt < 9; ++nt) acc[nt] = (f32x4){0.f, 0.f, 0.f, 0.f};

    const bf16* xrow = xn + (wave * 16 + l15) * 200 + q4 * 8;
    #pragma unroll
    for (int kb = 0; kb < 6; ++kb) {
        const bf16x8 a = *(const bf16x8*)(xrow + kb * 32);
        const bf16* wp = wrep + ((size_t)kb * 144 + l15) * 32 + q4 * 8;
        #pragma unroll
        for (int nt = 0; nt < 9; ++nt) {
            const bf16x8 bfr = *(const bf16x8*)(wp + (size_t)nt * 16 * 32);
            acc[nt] = __builtin_amdgcn_mfma_f32_16x16x32_bf16(a, bfr, acc[nt], 0, 0, 0);
        }
    }

    const int rw = rowbase + wave * 16 + q4 * 4;       // first of 4 D-rows
    #pragma unroll
    for (int nt = 0; nt < 9; ++nt) {
        const int col = nt * 16 + l15;
        const float bd = bias144[col];
        if (nt < 3) {
            #pragma unroll
            for (int reg = 0; reg < 4; ++reg)
                qo[(size_t)(rw + reg) * HK_ + col] = (f16)(acc[nt][reg] + bd);
        } else if (nt < 6) {
            #pragma unroll
            for (int reg = 0; reg < 4; ++reg)
                ko[(size_t)(rw + reg) * HK_ + (col - 48)] = (f16)(acc[nt][reg] + bd);
        } else {
            const int vcol = col - 96;
            const int h = vcol / 12, c12 = vcol % 12;
            f16x4 vv;
            #pragma unroll
            for (int reg = 0; reg < 4; ++reg) vv[reg] = (f16)(acc[nt][reg] + bd);
            *(f16x4*)(vt + ((size_t)(b * 4 + h) * 16 + c12) * 2048 +
                      lrow0 + wave * 16 + q4 * 4) = vv;
        }
    }
}

// ---------------------------------------------------------------------------
// K2a: MFMA attention partials (unchanged from round 7).
// ---------------------------------------------------------------------------
__global__ __launch_bounds__(256) void k_attn_part(
    const f16* __restrict__ qh, const f16* __restrict__ kh, const f16* __restrict__ vt,
    bf16* __restrict__ part_o, float* __restrict__ part_l)
{
    const int tid = threadIdx.x;
    const int wv = tid >> 6, lane = tid & 63;
    const int quad = lane >> 4, l15 = lane & 15;
    const int bh = blockIdx.x / 36;
    int r = blockIdx.x % 36;
    int qt = 0;
    while (r >= qt + 1) { r -= qt + 1; ++qt; }
    const int ks = r;
    const int b = bh >> 2, h = bh & 3;
    const size_t base  = (size_t)b * L_ * HK_ + h * 12;
    const size_t vbase = ((size_t)bh * 16 + l15) * 2048;
    const int kbase = ks * 256;
    const int qbase = qt * 256 + wv * 64;
    const bool diag = (ks == qt);
    const int ktmax = diag ? 4 * (wv + 1) : 16;

    f16x4 Qf[4];
    #pragma unroll
    for (int s = 0; s < 4; ++s) {
        f16x4 v; v[0] = 0; v[1] = 0; v[2] = 0; v[3] = 0;
        if (quad < 3)
            v = *(const f16x4*)(qh + base + (size_t)(qbase + s * 16 + l15) * HK_ + quad * 4);
        Qf[s] = v;
    }

    f32x4 O[4];
    #pragma unroll
    for (int s = 0; s < 4; ++s) O[s] = (f32x4){0.f, 0.f, 0.f, 0.f};

    for (int kt = 0; kt < ktmax; ++kt) {
        const int k0 = kbase + kt * 16 + quad * 4;
        f16x4 Kf; Kf[0] = 0; Kf[1] = 0; Kf[2] = 0; Kf[3] = 0;
        if (quad < 3)
            Kf = *(const f16x4*)(kh + base + (size_t)(kbase + kt * 16 + l15) * HK_ + quad * 4);
        const f16x4 Vf = *(const f16x4*)(vt + vbase + k0);
        #pragma unroll
        for (int s = 0; s < 4; ++s) {
            f32x4 sc = (f32x4){0.f, 0.f, 0.f, 0.f};
            sc = __builtin_amdgcn_mfma_f32_16x16x16f16(Kf, Qf[s], sc, 0, 0, 0);
            f16x4 p;
            if (diag) {
                const int qg = qbase + s * 16 + l15;
                #pragma unroll
                for (int j = 0; j < 4; ++j) {
                    float pv = __expf(sc[j] - 6.0f);
                    p[j] = (f16)((k0 + j <= qg) ? pv : 0.f);
                }
            } else {
                #pragma unroll
                for (int j = 0; j < 4; ++j)
                    p[j] = (f16)__expf(sc[j] - 6.0f);
            }
            O[s] = __builtin_amdgcn_mfma_f32_16x16x16f16(p, Vf, O[s], 0, 0, 0);
        }
    }

    #pragma unroll
    for (int s = 0; s < 4; ++s) {
        const int q16 = qbase + s * 16;
        #pragma unroll
        for (int j = 0; j < 4; ++j) {
            const int qq = q16 + quad * 4 + j;
            const size_t slot = ((size_t)bh * L_ + qq) * 8 + ks;
            if (l15 < 12)       part_o[slot * 12 + l15] = f2b(O[s][j]);
            else if (l15 == 12) part_l[slot] = O[s][j];
        }
    }
}

// ---------------------------------------------------------------------------
// K2b: combine partials -> ctx (bf16).
// ---------------------------------------------------------------------------
__global__ __launch_bounds__(256) void k_attn_comb(
    const bf16* __restrict__ part_o, const float* __restrict__ part_l,
    bf16* __restrict__ ctx)
{
    const int idx = blockIdx.x * 256 + threadIdx.x;   // bh*L + q
    const int bh = idx >> 11, q = idx & 2047;
    const int b = bh >> 2, h = bh & 3;
    const int ns = (q >> 8) + 1;
    const bf16* op = part_o + (size_t)idx * 96;
    const float* lp = part_l + (size_t)idx * 8;
    float l = 0.f, o[12];
    #pragma unroll
    for (int i = 0; i < 12; ++i) o[i] = 0.f;
    for (int s = 0; s < ns; ++s) {
        l += lp[s];
        #pragma unroll
        for (int i = 0; i < 12; ++i) o[i] += b2f(op[s * 12 + i]);
    }
    const float inv = 1.0f / l;
    bf16* cp = ctx + ((size_t)b * L_ + q) * HK_ + h * 12;
    #pragma unroll
    for (int i = 0; i < 12; ++i) cp[i] = f2b(o[i] * inv);
}

// ---------------------------------------------------------------------------
// K3: out-proj + residual + LN2 -> x2 (fp32) + xn2b (bf16).
// ---------------------------------------------------------------------------
__global__ __launch_bounds__(192) void k_proj_ln2(
    const float* __restrict__ x, const bf16* __restrict__ ctx,
    const float* __restrict__ wo, const float* __restrict__ bo,
    const float* __restrict__ g2, const float* __restrict__ lb2,
    float* __restrict__ x2, bf16* __restrict__ xn2b)
{
    __shared__ float cl[8 * HK_];
    __shared__ float x2l[8 * D_];
    const int tid = threadIdx.x;
    const int rowbase = blockIdx.x * 8;
    cl[tid]       = b2f(ctx[(size_t)rowbase * HK_ + tid]);
    cl[tid + 192] = b2f(ctx[(size_t)rowbase * HK_ + tid + 192]);
    __syncthreads();

    const int d = tid;
    float acc[8];
    #pragma unroll
    for (int r = 0; r < 8; ++r) acc[r] = 0.f;
    for (int j = 0; j < HK_; j += 4) {
        const float w0 = wo[(j + 0) * D_ + d];
        const float w1 = wo[(j + 1) * D_ + d];
        const float w2 = wo[(j + 2) * D_ + d];
        const float w3 = wo[(j + 3) * D_ + d];
        #pragma unroll
        for (int r = 0; r < 8; ++r) {
            const float4 cv = *(const float4*)&cl[r * HK_ + j];
            acc[r] = fmaf(cv.x, w0, fmaf(cv.y, w1, fmaf(cv.z, w2, fmaf(cv.w, w3, acc[r]))));
        }
    }
    const float bod = bo[d];
    #pragma unroll
    for (int r = 0; r < 8; ++r) {
        const size_t idx = (size_t)(rowbase + r) * D_ + d;
        const float v = acc[r] + bod + x[idx];
        x2[idx] = v;
        x2l[r * D_ + d] = v;
    }
    __syncthreads();

    const int wave = tid >> 6, lane = tid & 63;
    for (int r = wave; r < 8; r += 3) {
        const float x0  = x2l[r * D_ + lane];
        const float x1  = x2l[r * D_ + lane + 64];
        const float xv2 = x2l[r * D_ + lane + 128];
        float s = x0 + x1 + xv2;
        float q = x0 * x0 + x1 * x1 + xv2 * xv2;
        #pragma unroll
        for (int m = 1; m < 64; m <<= 1) {
            s += __shfl_xor(s, m, 64);
            q += __shfl_xor(q, m, 64);
        }
        const float mean = s * (1.0f / 192.0f);
        const float var  = q * (1.0f / 192.0f) - mean * mean;
        const float rs   = rsqrtf(var + EPS_);
        const size_t ro = (size_t)(rowbase + r) * D_;
        xn2b[ro + lane]       = f2b((x0 - mean) * rs * g2[lane]       + lb2[lane]);
        xn2b[ro + lane + 64]  = f2b((x1 - mean) * rs * g2[lane + 64]  + lb2[lane + 64]);
        xn2b[ro + lane + 128] = f2b((xv2 - mean) * rs * g2[lane + 128] + lb2[lane + 128]);
    }
}

// ---------------------------------------------------------------------------
// K-prep: repack conv weight [576][192] fp32 -> bf16 W'[kb][n][kk], kk=k%32.
// ---------------------------------------------------------------------------
__global__ __launch_bounds__(256) void k_wprep(
    const float* __restrict__ w, bf16* __restrict__ wr)
{
    const int i = blockIdx.x * 256 + threadIdx.x;   // i = k*192 + n
    if (i < 576 * 192) {
        const int k = i / 192, n = i - k * 192;
        wr[((size_t)(k >> 5) * 192 + n) * 32 + (k & 31)] = f2b(w[i]);
    }
}

// ---------------------------------------------------------------------------
// K4/K5: conv as MFMA GEMM (unchanged).
// ---------------------------------------------------------------------------
template <int IS_CONV1>
__global__ __launch_bounds__(256) void k_conv_mfma(
    const bf16* __restrict__ act, const bf16* __restrict__ wrep,
    const float* __restrict__ bias, const float* __restrict__ x2,
    bf16* __restrict__ outb, float* __restrict__ outf)
{
    const int wave = threadIdx.x >> 6, lane = threadIdx.x & 63;
    const int m16 = lane & 15, q = lane >> 4;
    const int rowbase = blockIdx.x * 64 + wave * 16;

    f32x4 acc[12];
    #pragma unroll
    for (int nt = 0; nt < 12; ++nt) acc[nt] = (f32x4){0.f, 0.f, 0.f, 0.f};

    #pragma unroll
    for (int t = 0; t < 3; ++t) {
        const long long arow = (long long)rowbase + m16 + t - 1;
        const bf16* ap = act + arow * D_ + q * 8;
        #pragma unroll
        for (int c6 = 0; c6 < 6; ++c6) {
            const int kb = t * 6 + c6;
            const bf16x8 a = *(const bf16x8*)(ap + c6 * 32);
            const bf16* wp = wrep + ((size_t)kb * 192 + m16) * 32 + q * 8;
            #pragma unroll
            for (int nt = 0; nt < 12; ++nt) {
                const bf16x8 b = *(const bf16x8*)(wp + (size_t)nt * 16 * 32);
                acc[nt] = __builtin_amdgcn_mfma_f32_16x16x32_bf16(a, b, acc[nt], 0, 0, 0);
            }
        }
    }

    #pragma unroll
    for (int nt = 0; nt < 12; ++nt) {
        const int col = nt * 16 + m16;
        const float bd = bias[col];
        #pragma unroll
        for (int reg = 0; reg < 4; ++reg) {
            const int r = rowbase + q * 4 + reg;
            const int m = r & (L_ - 1);
            const size_t idx = (size_t)r * D_ + col;
            if (IS_CONV1) {
                float v = fmaxf(acc[nt][reg] + bd, 0.f);
                if (m == 0 || m == L_ - 1) v = 0.f;
                outb[idx] = f2b(v);
            } else {
                float v = x2[idx];
                if (m != 0 && m != L_ - 1) v += acc[nt][reg] + bd;
                outf[idx] = v;
            }
        }
    }
}

// ---------------------------------------------------------------------------
extern "C" void kernel_launch(void* const* d_in, const int* in_sizes, int n_in,
                              void* d_out, int out_size, void* d_ws, size_t ws_size,
                              hipStream_t stream)
{
    const float* x    = (const float*)d_in[0];
    const float* ln1g = (const float*)d_in[1];
    const float* ln1b = (const float*)d_in[2];
    const float* wq   = (const float*)d_in[3];
    const float* bq   = (const float*)d_in[4];
    const float* wk   = (const float*)d_in[5];
    const float* bk   = (const float*)d_in[6];
    const float* wv   = (const float*)d_in[7];
    const float* bv   = (const float*)d_in[8];
    const float* wo   = (const float*)d_in[9];
    const float* bo   = (const float*)d_in[10];
    const float* ln2g = (const float*)d_in[11];
    const float* ln2b = (const float*)d_in[12];
    const float* c1w  = (const float*)d_in[13];
    const float* c1b  = (const float*)d_in[14];
    const float* c2w  = (const float*)d_in[15];
    const float* c2b  = (const float*)d_in[16];

    const size_t ROWS = (size_t)16 * L_;            // 32768
    char* ws = (char*)d_ws;
    size_t off = 4096;                               // guard (conv row -1)
    bf16* xn2b = (bf16*)(ws + off); off += ROWS * D_ * 2;    // 12.6 MB
    off += 4096;                                     // guard
    bf16* hpb  = (bf16*)(ws + off); off += ROWS * D_ * 2;    // 12.6 MB
    off += 4096;                                     // guard
    float* x2  = (float*)(ws + off); off += ROWS * D_ * 4;   // 25.2 MB
    f16* qb    = (f16*)(ws + off);   off += ROWS * HK_ * 2;  // 3.15 MB
    f16* kb    = (f16*)(ws + off);   off += ROWS * HK_ * 2;
    f16* vt    = (f16*)(ws + off);   off += (size_t)64 * 16 * 2048 * 2;  // 4.19 MB
    bf16* ctx  = (bf16*)(ws + off);  off += ROWS * HK_ * 2;
    bf16* wrep1 = (bf16*)(ws + off); off += 576 * 192 * 2;   // 221 KB
    bf16* wrep2 = (bf16*)(ws + off); off += 576 * 192 * 2;
    bf16* wrepq = (bf16*)(ws + off); off += 6 * 144 * 32 * 2; // 55 KB
    float* bias144 = (float*)(ws + off); off += 144 * 4;     // total ~66 MB

    // attention partials ALIAS later-written buffers (consumed by attn_comb
    // before proj_ln2 writes x2 / conv1 writes hpb):
    bf16*  part_o = (bf16*)x2;       // 25.17 MB (exactly fits x2 region)
    float* part_l = (float*)hpb;     //  4.2 MB

    k_wprep        <<<432, 256, 0, stream>>>(c1w, wrep1);
    k_wprep        <<<432, 256, 0, stream>>>(c2w, wrep2);
    k_wprep_qkv    <<<108, 256, 0, stream>>>(wq, wk, wv, bq, bk, bv, wrepq, bias144);
    k_ln_qkv       <<< 512, 256, 0, stream>>>(x, ln1g, ln1b, wrepq, bias144, qb, kb, vt);
    k_attn_part    <<<64 * 36, 256, 0, stream>>>(qb, kb, vt, part_o, part_l);
    k_attn_comb    <<< 512, 256, 0, stream>>>(part_o, part_l, ctx);
    k_proj_ln2     <<<4096, 192, 0, stream>>>(x, ctx, wo, bo, ln2g, ln2b, x2, xn2b);
    k_conv_mfma<1> <<< 512, 256, 0, stream>>>(xn2b, wrep1, c1b, nullptr, hpb, nullptr);
    k_conv_mfma<0> <<< 512, 256, 0, stream>>>(hpb, wrep2, c2b, x2, nullptr, (float*)d_out);
}

// Round 9
// 244.226 us; speedup vs baseline: 2.6691x; 1.0649x over previous
//
#include <hip/hip_runtime.h>
#include <hip/hip_bf16.h>

#define L_ 2048
#define D_ 192
#define HK_ 48
#define EPS_ 1e-3f
#define SCALE_ 0.28867513459481287f  // 1/sqrt(12)

typedef __hip_bfloat16 bf16;
typedef _Float16 f16;
typedef _Float16 f16x4 __attribute__((ext_vector_type(4)));
typedef __bf16 bf16x8 __attribute__((ext_vector_type(8)));
typedef float  f32x4  __attribute__((ext_vector_type(4)));

__device__ __forceinline__ float b2f(bf16 x) { return __bfloat162float(x); }
__device__ __forceinline__ bf16 f2b(float x) { return __float2bfloat16(x); }

// ---------------------------------------------------------------------------
// K0: single prep kernel — all weight repacks in one launch.
//  [0, 110592)        c1w  -> wrep1  bf16 [kb][n][kk]
//  [110592, 221184)   c2w  -> wrep2
//  [221184, 248832)   qkv  -> wrepq  bf16 [kb][n144][kk]  (q cols pre-scaled)
//  [248832, 248976)   bias144 (q part pre-scaled)
//  [248976, 261264)   wo   -> wrepo  bf16 [kb][n][kk], K padded 48->64 w/ 0
// ---------------------------------------------------------------------------
__global__ __launch_bounds__(256) void k_prep_all(
    const float* __restrict__ c1w, const float* __restrict__ c2w,
    const float* __restrict__ wq, const float* __restrict__ wk, const float* __restrict__ wv,
    const float* __restrict__ bq, const float* __restrict__ bk, const float* __restrict__ bv,
    const float* __restrict__ wo,
    bf16* __restrict__ wrep1, bf16* __restrict__ wrep2,
    bf16* __restrict__ wrepq, float* __restrict__ bias144, bf16* __restrict__ wrepo)
{
    const int i = blockIdx.x * 256 + threadIdx.x;
    if (i < 110592) {
        const int k = i / 192, n = i - k * 192;
        wrep1[((size_t)(k >> 5) * 192 + n) * 32 + (k & 31)] = f2b(c1w[i]);
    } else if (i < 221184) {
        const int j = i - 110592;
        const int k = j / 192, n = j - k * 192;
        wrep2[((size_t)(k >> 5) * 192 + n) * 32 + (k & 31)] = f2b(c2w[j]);
    } else if (i < 248832) {
        const int j = i - 221184;
        const int kb = j / 4608, rem = j % 4608;
        const int n = rem / 32, kk = rem % 32;
        const int k = kb * 32 + kk;
        float v;
        if (n < 48)       v = wq[k * HK_ + n] * SCALE_;
        else if (n < 96)  v = wk[k * HK_ + (n - 48)];
        else              v = wv[k * HK_ + (n - 96)];
        wrepq[j] = f2b(v);
    } else if (i < 248976) {
        const int j = i - 248832;
        bias144[j] = (j < 48) ? bq[j] * SCALE_
                   : (j < 96) ? bk[j - 48] : bv[j - 96];
    } else if (i < 261264) {
        const int j = i - 248976;
        const int kb = j / 6144, rem = j % 6144;
        const int n = rem / 32, kk = rem % 32;
        const int k = kb * 32 + kk;
        wrepo[j] = f2b(k < 48 ? wo[k * D_ + n] : 0.f);
    }
}

// ---------------------------------------------------------------------------
// K1: fused LN1 + QKV projection via MFMA. 64 rows/block, 256 threads.
// (unchanged from round 8)
// ---------------------------------------------------------------------------
__global__ __launch_bounds__(256) void k_ln_qkv(
    const float* __restrict__ x, const float* __restrict__ g1, const float* __restrict__ b1,
    const bf16* __restrict__ wrep, const float* __restrict__ bias144,
    f16* __restrict__ qo, f16* __restrict__ ko, f16* __restrict__ vt)
{
    __shared__ bf16 xn[64 * 200];
    const int tid = threadIdx.x;
    const int wave = tid >> 6, lane = tid & 63;
    const int rowbase = blockIdx.x * 64;
    const int b = rowbase >> 11;
    const int lrow0 = rowbase & 2047;

    const float gg0 = g1[lane], gg1 = g1[lane + 64], gg2 = g1[lane + 128];
    const float bb0 = b1[lane], bb1 = b1[lane + 64], bb2 = b1[lane + 128];
    for (int i = 0; i < 16; ++i) {
        const int r = wave * 16 + i;
        const float* xp = x + (size_t)(rowbase + r) * D_;
        const float x0 = xp[lane];
        const float x1 = xp[lane + 64];
        const float x2 = xp[lane + 128];
        float s = x0 + x1 + x2;
        float q = x0 * x0 + x1 * x1 + x2 * x2;
        #pragma unroll
        for (int m = 1; m < 64; m <<= 1) {
            s += __shfl_xor(s, m, 64);
            q += __shfl_xor(q, m, 64);
        }
        const float mean = s * (1.0f / 192.0f);
        const float var  = q * (1.0f / 192.0f) - mean * mean;
        const float rs   = rsqrtf(var + EPS_);
        xn[r * 200 + lane]       = f2b((x0 - mean) * rs * gg0 + bb0);
        xn[r * 200 + lane + 64]  = f2b((x1 - mean) * rs * gg1 + bb1);
        xn[r * 200 + lane + 128] = f2b((x2 - mean) * rs * gg2 + bb2);
    }

    // ones/zeros vt columns (vcol 12..15) for this block's 64 positions
    {
        const int h  = tid >> 6;
        const int vc = 12 + ((tid >> 4) & 3);
        const int p0 = lrow0 + (tid & 15) * 4;
        f16x4 vv;
        vv[0] = vv[1] = vv[2] = vv[3] = (vc == 12) ? (f16)1.0f : (f16)0.0f;
        *(f16x4*)(vt + ((size_t)(b * 4 + h) * 16 + vc) * 2048 + p0) = vv;
    }
    __syncthreads();

    const int l15 = lane & 15, q4 = lane >> 4;
    f32x4 acc[9];
    #pragma unroll
    for (int nt = 0; nt < 9; ++nt) acc[nt] = (f32x4){0.f, 0.f, 0.f, 0.f};

    const bf16* xrow = xn + (wave * 16 + l15) * 200 + q4 * 8;
    #pragma unroll
    for (int kb = 0; kb < 6; ++kb) {
        const bf16x8 a = *(const bf16x8*)(xrow + kb * 32);
        const bf16* wp = wrep + ((size_t)kb * 144 + l15) * 32 + q4 * 8;
        #pragma unroll
        for (int nt = 0; nt < 9; ++nt) {
            const bf16x8 bfr = *(const bf16x8*)(wp + (size_t)nt * 16 * 32);
            acc[nt] = __builtin_amdgcn_mfma_f32_16x16x32_bf16(a, bfr, acc[nt], 0, 0, 0);
        }
    }

    const int rw = rowbase + wave * 16 + q4 * 4;
    #pragma unroll
    for (int nt = 0; nt < 9; ++nt) {
        const int col = nt * 16 + l15;
        const float bd = bias144[col];
        if (nt < 3) {
            #pragma unroll
            for (int reg = 0; reg < 4; ++reg)
                qo[(size_t)(rw + reg) * HK_ + col] = (f16)(acc[nt][reg] + bd);
        } else if (nt < 6) {
            #pragma unroll
            for (int reg = 0; reg < 4; ++reg)
                ko[(size_t)(rw + reg) * HK_ + (col - 48)] = (f16)(acc[nt][reg] + bd);
        } else {
            const int vcol = col - 96;
            const int h = vcol / 12, c12 = vcol % 12;
            f16x4 vv;
            #pragma unroll
            for (int reg = 0; reg < 4; ++reg) vv[reg] = (f16)(acc[nt][reg] + bd);
            *(f16x4*)(vt + ((size_t)(b * 4 + h) * 16 + c12) * 2048 +
                      lrow0 + wave * 16 + q4 * 4) = vv;
        }
    }
}

// ---------------------------------------------------------------------------
// K2: MFMA attention partials. Softmax shift folded into the S-MFMA via
// padded hd 12: Q[12]=1 (quad3 const), K[12]=-6 -> sc = q.k - 6 directly.
// Partials in [bh][ks][q] layout (contiguous per block -> coalesced writes).
// ---------------------------------------------------------------------------
__global__ __launch_bounds__(256) void k_attn_part(
    const f16* __restrict__ qh, const f16* __restrict__ kh, const f16* __restrict__ vt,
    bf16* __restrict__ part_o, float* __restrict__ part_l)
{
    const int tid = threadIdx.x;
    const int wv = tid >> 6, lane = tid & 63;
    const int quad = lane >> 4, l15 = lane & 15;
    const int bh = blockIdx.x / 36;
    int r = blockIdx.x % 36;
    int qt = 0;
    while (r >= qt + 1) { r -= qt + 1; ++qt; }
    const int ks = r;
    const int b = bh >> 2, h = bh & 3;
    const size_t base  = (size_t)b * L_ * HK_ + h * 12;
    const size_t vbase = ((size_t)bh * 16 + l15) * 2048;
    const int kbase = ks * 256;
    const int qbase = qt * 256 + wv * 64;
    const bool diag = (ks == qt);
    const int ktmax = diag ? 4 * (wv + 1) : 16;

    f16x4 Qf[4];
    #pragma unroll
    for (int s = 0; s < 4; ++s) {
        f16x4 v;
        if (quad < 3)
            v = *(const f16x4*)(qh + base + (size_t)(qbase + s * 16 + l15) * HK_ + quad * 4);
        else { v[0] = (f16)1.0f; v[1] = 0; v[2] = 0; v[3] = 0; }   // hd12 = 1
        Qf[s] = v;
    }

    f32x4 O[4];
    #pragma unroll
    for (int s = 0; s < 4; ++s) O[s] = (f32x4){0.f, 0.f, 0.f, 0.f};

    for (int kt = 0; kt < ktmax; ++kt) {
        const int k0 = kbase + kt * 16 + quad * 4;
        f16x4 Kf;
        if (quad < 3)
            Kf = *(const f16x4*)(kh + base + (size_t)(kbase + kt * 16 + l15) * HK_ + quad * 4);
        else { Kf[0] = (f16)-6.0f; Kf[1] = 0; Kf[2] = 0; Kf[3] = 0; } // hd12 = -6
        const f16x4 Vf = *(const f16x4*)(vt + vbase + k0);
        #pragma unroll
        for (int s = 0; s < 4; ++s) {
            f32x4 sc = (f32x4){0.f, 0.f, 0.f, 0.f};
            sc = __builtin_amdgcn_mfma_f32_16x16x16f16(Kf, Qf[s], sc, 0, 0, 0);
            f16x4 p;
            if (diag) {
                const int qg = qbase + s * 16 + l15;
                #pragma unroll
                for (int j = 0; j < 4; ++j) {
                    float pv = __expf(sc[j]);
                    p[j] = (f16)((k0 + j <= qg) ? pv : 0.f);
                }
            } else {
                #pragma unroll
                for (int j = 0; j < 4; ++j)
                    p[j] = (f16)__expf(sc[j]);
            }
            O[s] = __builtin_amdgcn_mfma_f32_16x16x16f16(p, Vf, O[s], 0, 0, 0);
        }
    }

    const size_t pobase = (size_t)(bh * 8 + ks) * 2048;
    #pragma unroll
    for (int s = 0; s < 4; ++s) {
        const int q16 = qbase + s * 16;
        #pragma unroll
        for (int j = 0; j < 4; ++j) {
            const int qq = q16 + quad * 4 + j;
            if (l15 < 12)       part_o[(pobase + qq) * 12 + l15] = f2b(O[s][j]);
            else if (l15 == 12) part_l[pobase + qq] = O[s][j];
        }
    }
}

// ---------------------------------------------------------------------------
// K3: fused combine + out-proj (MFMA) + residual + LN2.
// 64 rows/block, 256 threads. Phase 1: sum partial slices -> ctx tile (bf16)
// in LDS (stride 72: 2-way bank alias, free). Phase 2: GEMM K=48 padded to 64
// vs prepacked wo. Phase 3: +bias +x residual -> x2b (bf16), then LN2 via
// 16-lane shuffle row-reduction -> xn2b (bf16).
// ---------------------------------------------------------------------------
__global__ __launch_bounds__(256) void k_proj_ln2(
    const float* __restrict__ x, const bf16* __restrict__ part_o,
    const float* __restrict__ part_l, const bf16* __restrict__ wrepo,
    const float* __restrict__ bo, const float* __restrict__ g2,
    const float* __restrict__ lb2, bf16* __restrict__ x2b,
    bf16* __restrict__ xn2b)
{
    __shared__ bf16 ct[64 * 72];
    const int tid = threadIdx.x;
    const int wave = tid >> 6, lane = tid & 63;
    const int rowbase = blockIdx.x * 64;
    const int b = rowbase >> 11, lrow = rowbase & 2047;
    const int ns = (lrow >> 8) + 1;          // same for all 64 rows (64 | 256)

    // phase 1: combine partials -> ctx tile
    {
        const int rr = tid >> 2, h = tid & 3;
        const int q = lrow + rr;
        const bf16* op = part_o + ((size_t)(b * 4 + h) * 8 * 2048 + q) * 12;
        const float* lp = part_l + (size_t)(b * 4 + h) * 8 * 2048 + q;
        float o[12];
        #pragma unroll
        for (int i = 0; i < 12; ++i) o[i] = 0.f;
        float l = 0.f;
        for (int s = 0; s < ns; ++s) {
            l += lp[(size_t)s * 2048];
            #pragma unroll
            for (int i = 0; i < 12; ++i) o[i] += b2f(op[(size_t)s * 2048 * 12 + i]);
        }
        const float inv = 1.0f / l;
        #pragma unroll
        for (int i = 0; i < 12; ++i) ct[rr * 72 + h * 12 + i] = f2b(o[i] * inv);
        const int c0 = 48 + h * 4;           // zero pad cols 48..63
        #pragma unroll
        for (int i = 0; i < 4; ++i) ct[rr * 72 + c0 + i] = f2b(0.f);
    }
    __syncthreads();

    // phase 2: out-projection GEMM
    const int l15 = lane & 15, q4 = lane >> 4;
    f32x4 acc[12];
    #pragma unroll
    for (int nt = 0; nt < 12; ++nt) acc[nt] = (f32x4){0.f, 0.f, 0.f, 0.f};
    const bf16* arow = ct + (wave * 16 + l15) * 72 + q4 * 8;
    #pragma unroll
    for (int kb = 0; kb < 2; ++kb) {
        const bf16x8 a = *(const bf16x8*)(arow + kb * 32);
        const bf16* wp = wrepo + ((size_t)kb * 192 + l15) * 32 + q4 * 8;
        #pragma unroll
        for (int nt = 0; nt < 12; ++nt) {
            const bf16x8 bb = *(const bf16x8*)(wp + (size_t)nt * 16 * 32);
            acc[nt] = __builtin_amdgcn_mfma_f32_16x16x32_bf16(a, bb, acc[nt], 0, 0, 0);
        }
    }

    // phase 3: +bias +residual -> x2b; LN2 -> xn2b
    const int rw0 = rowbase + wave * 16 + q4 * 4;
    float sum[4] = {0.f, 0.f, 0.f, 0.f}, ssum[4] = {0.f, 0.f, 0.f, 0.f};
    #pragma unroll
    for (int nt = 0; nt < 12; ++nt) {
        const int col = nt * 16 + l15;
        const float bod = bo[col];
        #pragma unroll
        for (int reg = 0; reg < 4; ++reg) {
            const float v = acc[nt][reg] + bod + x[(size_t)(rw0 + reg) * D_ + col];
            acc[nt][reg] = v;
            x2b[(size_t)(rw0 + reg) * D_ + col] = f2b(v);
            sum[reg] += v; ssum[reg] += v * v;
        }
    }
    #pragma unroll
    for (int m = 1; m <= 8; m <<= 1) {
        #pragma unroll
        for (int reg = 0; reg < 4; ++reg) {
            sum[reg]  += __shfl_xor(sum[reg], m, 64);
            ssum[reg] += __shfl_xor(ssum[reg], m, 64);
        }
    }
    float mean[4], rs[4];
    #pragma unroll
    for (int reg = 0; reg < 4; ++reg) {
        mean[reg] = sum[reg] * (1.0f / 192.0f);
        const float var = ssum[reg] * (1.0f / 192.0f) - mean[reg] * mean[reg];
        rs[reg] = rsqrtf(var + EPS_);
    }
    #pragma unroll
    for (int nt = 0; nt < 12; ++nt) {
        const int col = nt * 16 + l15;
        const float g = g2[col], bb2 = lb2[col];
        #pragma unroll
        for (int reg = 0; reg < 4; ++reg)
            xn2b[(size_t)(rw0 + reg) * D_ + col] =
                f2b((acc[nt][reg] - mean[reg]) * rs[reg] * g + bb2);
    }
}

// ---------------------------------------------------------------------------
// K4/K5: conv as MFMA GEMM. conv2's residual input x2 is now bf16.
// ---------------------------------------------------------------------------
template <int IS_CONV1>
__global__ __launch_bounds__(256) void k_conv_mfma(
    const bf16* __restrict__ act, const bf16* __restrict__ wrep,
    const float* __restrict__ bias, const bf16* __restrict__ x2b,
    bf16* __restrict__ outb, float* __restrict__ outf)
{
    const int wave = threadIdx.x >> 6, lane = threadIdx.x & 63;
    const int m16 = lane & 15, q = lane >> 4;
    const int rowbase = blockIdx.x * 64 + wave * 16;

    f32x4 acc[12];
    #pragma unroll
    for (int nt = 0; nt < 12; ++nt) acc[nt] = (f32x4){0.f, 0.f, 0.f, 0.f};

    #pragma unroll
    for (int t = 0; t < 3; ++t) {
        const long long arow = (long long)rowbase + m16 + t - 1;
        const bf16* ap = act + arow * D_ + q * 8;
        #pragma unroll
        for (int c6 = 0; c6 < 6; ++c6) {
            const int kb = t * 6 + c6;
            const bf16x8 a = *(const bf16x8*)(ap + c6 * 32);
            const bf16* wp = wrep + ((size_t)kb * 192 + m16) * 32 + q * 8;
            #pragma unroll
            for (int nt = 0; nt < 12; ++nt) {
                const bf16x8 b = *(const bf16x8*)(wp + (size_t)nt * 16 * 32);
                acc[nt] = __builtin_amdgcn_mfma_f32_16x16x32_bf16(a, b, acc[nt], 0, 0, 0);
            }
        }
    }

    #pragma unroll
    for (int nt = 0; nt < 12; ++nt) {
        const int col = nt * 16 + m16;
        const float bd = bias[col];
        #pragma unroll
        for (int reg = 0; reg < 4; ++reg) {
            const int r = rowbase + q * 4 + reg;
            const int m = r & (L_ - 1);
            const size_t idx = (size_t)r * D_ + col;
            if (IS_CONV1) {
                float v = fmaxf(acc[nt][reg] + bd, 0.f);
                if (m == 0 || m == L_ - 1) v = 0.f;
                outb[idx] = f2b(v);
            } else {
                float v = b2f(x2b[idx]);
                if (m != 0 && m != L_ - 1) v += acc[nt][reg] + bd;
                outf[idx] = v;
            }
        }
    }
}

// ---------------------------------------------------------------------------
extern "C" void kernel_launch(void* const* d_in, const int* in_sizes, int n_in,
                              void* d_out, int out_size, void* d_ws, size_t ws_size,
                              hipStream_t stream)
{
    const float* x    = (const float*)d_in[0];
    const float* ln1g = (const float*)d_in[1];
    const float* ln1b = (const float*)d_in[2];
    const float* wq   = (const float*)d_in[3];
    const float* bq   = (const float*)d_in[4];
    const float* wk   = (const float*)d_in[5];
    const float* bk   = (const float*)d_in[6];
    const float* wv   = (const float*)d_in[7];
    const float* bv   = (const float*)d_in[8];
    const float* wo   = (const float*)d_in[9];
    const float* bo   = (const float*)d_in[10];
    const float* ln2g = (const float*)d_in[11];
    const float* ln2b = (const float*)d_in[12];
    const float* c1w  = (const float*)d_in[13];
    const float* c1b  = (const float*)d_in[14];
    const float* c2w  = (const float*)d_in[15];
    const float* c2b  = (const float*)d_in[16];

    const size_t ROWS = (size_t)16 * L_;            // 32768
    char* ws = (char*)d_ws;
    size_t off = 4096;                               // guard (conv row -1)
    bf16* xn2b = (bf16*)(ws + off); off += ROWS * D_ * 2;    // 12.6 MB
    off += 4096;                                     // guard
    bf16* hpb  = (bf16*)(ws + off); off += ROWS * D_ * 2;    // 12.6 MB
    off += 4096;                                     // guard
    bf16* x2b  = (bf16*)(ws + off); off += ROWS * D_ * 2;    // 12.6 MB
    f16* qb    = (f16*)(ws + off);   off += ROWS * HK_ * 2;  // 3.15 MB
    f16* kb    = (f16*)(ws + off);   off += ROWS * HK_ * 2;
    f16* vt    = (f16*)(ws + off);   off += (size_t)64 * 16 * 2048 * 2;   // 4.19 MB
    bf16* part_o = (bf16*)(ws + off); off += (size_t)64 * 8 * 2048 * 12 * 2; // 25.2 MB
    float* part_l = (float*)(ws + off); off += (size_t)64 * 8 * 2048 * 4;    //  4.2 MB
    bf16* wrep1 = (bf16*)(ws + off); off += 576 * 192 * 2;   // 221 KB
    bf16* wrep2 = (bf16*)(ws + off); off += 576 * 192 * 2;
    bf16* wrepq = (bf16*)(ws + off); off += 6 * 144 * 32 * 2;
    float* bias144 = (float*)(ws + off); off += 144 * 4;
    bf16* wrepo = (bf16*)(ws + off); off += 2 * 192 * 32 * 2; // total ~83 MB

    k_prep_all     <<<1021, 256, 0, stream>>>(c1w, c2w, wq, wk, wv, bq, bk, bv, wo,
                                              wrep1, wrep2, wrepq, bias144, wrepo);
    k_ln_qkv       <<< 512, 256, 0, stream>>>(x, ln1g, ln1b, wrepq, bias144, qb, kb, vt);
    k_attn_part    <<<64 * 36, 256, 0, stream>>>(qb, kb, vt, part_o, part_l);
    k_proj_ln2     <<< 512, 256, 0, stream>>>(x, part_o, part_l, wrepo, bo, ln2g, ln2b,
                                              x2b, xn2b);
    k_conv_mfma<1> <<< 512, 256, 0, stream>>>(xn2b, wrep1, c1b, nullptr, hpb, nullptr);
    k_conv_mfma<0> <<< 512, 256, 0, stream>>>(hpb, wrep2, c2b, x2b, nullptr, (float*)d_out);
}

// Round 11
// 243.760 us; speedup vs baseline: 2.6742x; 1.0019x over previous
//
#include <hip/hip_runtime.h>
#include <hip/hip_bf16.h>

#define L_ 2048
#define D_ 192
#define HK_ 48
#define EPS_ 1e-3f
#define SCALE_ 0.28867513459481287f  // 1/sqrt(12)

typedef __hip_bfloat16 bf16;
typedef _Float16 f16;
typedef __fp16 hf16x2 __attribute__((ext_vector_type(2)));   // builtin return type
typedef _Float16 f16x4 __attribute__((ext_vector_type(4)));
typedef __bf16 bf16x8 __attribute__((ext_vector_type(8)));
typedef float  f32x4  __attribute__((ext_vector_type(4)));

__device__ __forceinline__ float b2f(bf16 x) { return __bfloat162float(x); }
__device__ __forceinline__ bf16 f2b(float x) { return __float2bfloat16(x); }

// ---------------------------------------------------------------------------
// K0: single prep kernel — all weight repacks in one launch (unchanged).
// ---------------------------------------------------------------------------
__global__ __launch_bounds__(256) void k_prep_all(
    const float* __restrict__ c1w, const float* __restrict__ c2w,
    const float* __restrict__ wq, const float* __restrict__ wk, const float* __restrict__ wv,
    const float* __restrict__ bq, const float* __restrict__ bk, const float* __restrict__ bv,
    const float* __restrict__ wo,
    bf16* __restrict__ wrep1, bf16* __restrict__ wrep2,
    bf16* __restrict__ wrepq, float* __restrict__ bias144, bf16* __restrict__ wrepo)
{
    const int i = blockIdx.x * 256 + threadIdx.x;
    if (i < 110592) {
        const int k = i / 192, n = i - k * 192;
        wrep1[((size_t)(k >> 5) * 192 + n) * 32 + (k & 31)] = f2b(c1w[i]);
    } else if (i < 221184) {
        const int j = i - 110592;
        const int k = j / 192, n = j - k * 192;
        wrep2[((size_t)(k >> 5) * 192 + n) * 32 + (k & 31)] = f2b(c2w[j]);
    } else if (i < 248832) {
        const int j = i - 221184;
        const int kb = j / 4608, rem = j % 4608;
        const int n = rem / 32, kk = rem % 32;
        const int k = kb * 32 + kk;
        float v;
        if (n < 48)       v = wq[k * HK_ + n] * SCALE_;
        else if (n < 96)  v = wk[k * HK_ + (n - 48)];
        else              v = wv[k * HK_ + (n - 96)];
        wrepq[j] = f2b(v);
    } else if (i < 248976) {
        const int j = i - 248832;
        bias144[j] = (j < 48) ? bq[j] * SCALE_
                   : (j < 96) ? bk[j - 48] : bv[j - 96];
    } else if (i < 261264) {
        const int j = i - 248976;
        const int kb = j / 6144, rem = j % 6144;
        const int n = rem / 32, kk = rem % 32;
        const int k = kb * 32 + kk;
        wrepo[j] = f2b(k < 48 ? wo[k * D_ + n] : 0.f);
    }
}

// ---------------------------------------------------------------------------
// K1: fused LN1 + QKV projection via MFMA (unchanged from round 9).
// ---------------------------------------------------------------------------
__global__ __launch_bounds__(256) void k_ln_qkv(
    const float* __restrict__ x, const float* __restrict__ g1, const float* __restrict__ b1,
    const bf16* __restrict__ wrep, const float* __restrict__ bias144,
    f16* __restrict__ qo, f16* __restrict__ ko, f16* __restrict__ vt)
{
    __shared__ bf16 xn[64 * 200];
    const int tid = threadIdx.x;
    const int wave = tid >> 6, lane = tid & 63;
    const int rowbase = blockIdx.x * 64;
    const int b = rowbase >> 11;
    const int lrow0 = rowbase & 2047;

    const float gg0 = g1[lane], gg1 = g1[lane + 64], gg2 = g1[lane + 128];
    const float bb0 = b1[lane], bb1 = b1[lane + 64], bb2 = b1[lane + 128];
    for (int i = 0; i < 16; ++i) {
        const int r = wave * 16 + i;
        const float* xp = x + (size_t)(rowbase + r) * D_;
        const float x0 = xp[lane];
        const float x1 = xp[lane + 64];
        const float x2 = xp[lane + 128];
        float s = x0 + x1 + x2;
        float q = x0 * x0 + x1 * x1 + x2 * x2;
        #pragma unroll
        for (int m = 1; m < 64; m <<= 1) {
            s += __shfl_xor(s, m, 64);
            q += __shfl_xor(q, m, 64);
        }
        const float mean = s * (1.0f / 192.0f);
        const float var  = q * (1.0f / 192.0f) - mean * mean;
        const float rs   = rsqrtf(var + EPS_);
        xn[r * 200 + lane]       = f2b((x0 - mean) * rs * gg0 + bb0);
        xn[r * 200 + lane + 64]  = f2b((x1 - mean) * rs * gg1 + bb1);
        xn[r * 200 + lane + 128] = f2b((x2 - mean) * rs * gg2 + bb2);
    }

    {
        const int h  = tid >> 6;
        const int vc = 12 + ((tid >> 4) & 3);
        const int p0 = lrow0 + (tid & 15) * 4;
        f16x4 vv;
        vv[0] = vv[1] = vv[2] = vv[3] = (vc == 12) ? (f16)1.0f : (f16)0.0f;
        *(f16x4*)(vt + ((size_t)(b * 4 + h) * 16 + vc) * 2048 + p0) = vv;
    }
    __syncthreads();

    const int l15 = lane & 15, q4 = lane >> 4;
    f32x4 acc[9];
    #pragma unroll
    for (int nt = 0; nt < 9; ++nt) acc[nt] = (f32x4){0.f, 0.f, 0.f, 0.f};

    const bf16* xrow = xn + (wave * 16 + l15) * 200 + q4 * 8;
    #pragma unroll
    for (int kb = 0; kb < 6; ++kb) {
        const bf16x8 a = *(const bf16x8*)(xrow + kb * 32);
        const bf16* wp = wrep + ((size_t)kb * 144 + l15) * 32 + q4 * 8;
        #pragma unroll
        for (int nt = 0; nt < 9; ++nt) {
            const bf16x8 bfr = *(const bf16x8*)(wp + (size_t)nt * 16 * 32);
            acc[nt] = __builtin_amdgcn_mfma_f32_16x16x32_bf16(a, bfr, acc[nt], 0, 0, 0);
        }
    }

    const int rw = rowbase + wave * 16 + q4 * 4;
    #pragma unroll
    for (int nt = 0; nt < 9; ++nt) {
        const int col = nt * 16 + l15;
        const float bd = bias144[col];
        if (nt < 3) {
            #pragma unroll
            for (int reg = 0; reg < 4; ++reg)
                qo[(size_t)(rw + reg) * HK_ + col] = (f16)(acc[nt][reg] + bd);
        } else if (nt < 6) {
            #pragma unroll
            for (int reg = 0; reg < 4; ++reg)
                ko[(size_t)(rw + reg) * HK_ + (col - 48)] = (f16)(acc[nt][reg] + bd);
        } else {
            const int vcol = col - 96;
            const int h = vcol / 12, c12 = vcol % 12;
            f16x4 vv;
            #pragma unroll
            for (int reg = 0; reg < 4; ++reg) vv[reg] = (f16)(acc[nt][reg] + bd);
            *(f16x4*)(vt + ((size_t)(b * 4 + h) * 16 + c12) * 2048 +
                      lrow0 + wave * 16 + q4 * 4) = vv;
        }
    }
}

// ---------------------------------------------------------------------------
// K2: MFMA attention partials. kt-loop grouped by 4 with register prefetch
// (ktmax is always a multiple of 4): 8 independent loads in flight per group
// hide L2 latency. P packed via v_cvt_pkrtz_f16_f32.
// ---------------------------------------------------------------------------
__global__ __launch_bounds__(256) void k_attn_part(
    const f16* __restrict__ qh, const f16* __restrict__ kh, const f16* __restrict__ vt,
    bf16* __restrict__ part_o, float* __restrict__ part_l)
{
    const int tid = threadIdx.x;
    const int wv = tid >> 6, lane = tid & 63;
    const int quad = lane >> 4, l15 = lane & 15;
    const int bh = blockIdx.x / 36;
    int r = blockIdx.x % 36;
    int qt = 0;
    while (r >= qt + 1) { r -= qt + 1; ++qt; }
    const int ks = r;
    const int b = bh >> 2, h = bh & 3;
    const size_t base  = (size_t)b * L_ * HK_ + h * 12;
    const size_t vbase = ((size_t)bh * 16 + l15) * 2048;
    const int kbase = ks * 256;
    const int qbase = qt * 256 + wv * 64;
    const bool diag = (ks == qt);
    const int ktmax = diag ? 4 * (wv + 1) : 16;

    f16x4 Qf[4];
    #pragma unroll
    for (int s = 0; s < 4; ++s) {
        f16x4 v;
        if (quad < 3)
            v = *(const f16x4*)(qh + base + (size_t)(qbase + s * 16 + l15) * HK_ + quad * 4);
        else { v[0] = (f16)1.0f; v[1] = 0; v[2] = 0; v[3] = 0; }   // hd12 = 1
        Qf[s] = v;
    }

    f32x4 O[4];
    #pragma unroll
    for (int s = 0; s < 4; ++s) O[s] = (f32x4){0.f, 0.f, 0.f, 0.f};

    for (int g = 0; g < ktmax; g += 4) {
        f16x4 Kg[4], Vg[4];
        #pragma unroll
        for (int u = 0; u < 4; ++u) {
            const int kt = g + u;
            f16x4 kf;
            if (quad < 3)
                kf = *(const f16x4*)(kh + base + (size_t)(kbase + kt * 16 + l15) * HK_ + quad * 4);
            else { kf[0] = (f16)-6.0f; kf[1] = 0; kf[2] = 0; kf[3] = 0; } // hd12 = -6
            Kg[u] = kf;
            Vg[u] = *(const f16x4*)(vt + vbase + kbase + kt * 16 + quad * 4);
        }
        #pragma unroll
        for (int u = 0; u < 4; ++u) {
            const int k0 = kbase + (g + u) * 16 + quad * 4;
            #pragma unroll
            for (int s = 0; s < 4; ++s) {
                f32x4 sc = (f32x4){0.f, 0.f, 0.f, 0.f};
                sc = __builtin_amdgcn_mfma_f32_16x16x16f16(Kg[u], Qf[s], sc, 0, 0, 0);
                float p0 = __expf(sc[0]), p1 = __expf(sc[1]);
                float p2 = __expf(sc[2]), p3 = __expf(sc[3]);
                if (diag) {
                    const int qg = qbase + s * 16 + l15;
                    p0 = (k0 + 0 <= qg) ? p0 : 0.f;
                    p1 = (k0 + 1 <= qg) ? p1 : 0.f;
                    p2 = (k0 + 2 <= qg) ? p2 : 0.f;
                    p3 = (k0 + 3 <= qg) ? p3 : 0.f;
                }
                const hf16x2 lo = __builtin_amdgcn_cvt_pkrtz(p0, p1);
                const hf16x2 hi = __builtin_amdgcn_cvt_pkrtz(p2, p3);
                f16x4 p;
                p[0] = (f16)lo[0]; p[1] = (f16)lo[1];
                p[2] = (f16)hi[0]; p[3] = (f16)hi[1];
                O[s] = __builtin_amdgcn_mfma_f32_16x16x16f16(p, Vg[u], O[s], 0, 0, 0);
            }
        }
    }

    const size_t pobase = (size_t)(bh * 8 + ks) * 2048;
    #pragma unroll
    for (int s = 0; s < 4; ++s) {
        const int q16 = qbase + s * 16;
        #pragma unroll
        for (int j = 0; j < 4; ++j) {
            const int qq = q16 + quad * 4 + j;
            if (l15 < 12)       part_o[(pobase + qq) * 12 + l15] = f2b(O[s][j]);
            else if (l15 == 12) part_l[pobase + qq] = O[s][j];
        }
    }
}

// ---------------------------------------------------------------------------
// K3: fused combine + out-proj (MFMA) + residual + LN2 (unchanged).
// ---------------------------------------------------------------------------
__global__ __launch_bounds__(256) void k_proj_ln2(
    const float* __restrict__ x, const bf16* __restrict__ part_o,
    const float* __restrict__ part_l, const bf16* __restrict__ wrepo,
    const float* __restrict__ bo, const float* __restrict__ g2,
    const float* __restrict__ lb2, bf16* __restrict__ x2b,
    bf16* __restrict__ xn2b)
{
    __shared__ bf16 ct[64 * 72];
    const int tid = threadIdx.x;
    const int wave = tid >> 6, lane = tid & 63;
    const int rowbase = blockIdx.x * 64;
    const int b = rowbase >> 11, lrow = rowbase & 2047;
    const int ns = (lrow >> 8) + 1;

    {
        const int rr = tid >> 2, h = tid & 3;
        const int q = lrow + rr;
        const bf16* op = part_o + ((size_t)(b * 4 + h) * 8 * 2048 + q) * 12;
        const float* lp = part_l + (size_t)(b * 4 + h) * 8 * 2048 + q;
        float o[12];
        #pragma unroll
        for (int i = 0; i < 12; ++i) o[i] = 0.f;
        float l = 0.f;
        for (int s = 0; s < ns; ++s) {
            l += lp[(size_t)s * 2048];
            #pragma unroll
            for (int i = 0; i < 12; ++i) o[i] += b2f(op[(size_t)s * 2048 * 12 + i]);
        }
        const float inv = 1.0f / l;
        #pragma unroll
        for (int i = 0; i < 12; ++i) ct[rr * 72 + h * 12 + i] = f2b(o[i] * inv);
        const int c0 = 48 + h * 4;
        #pragma unroll
        for (int i = 0; i < 4; ++i) ct[rr * 72 + c0 + i] = f2b(0.f);
    }
    __syncthreads();

    const int l15 = lane & 15, q4 = lane >> 4;
    f32x4 acc[12];
    #pragma unroll
    for (int nt = 0; nt < 12; ++nt) acc[nt] = (f32x4){0.f, 0.f, 0.f, 0.f};
    const bf16* arow = ct + (wave * 16 + l15) * 72 + q4 * 8;
    #pragma unroll
    for (int kb = 0; kb < 2; ++kb) {
        const bf16x8 a = *(const bf16x8*)(arow + kb * 32);
        const bf16* wp = wrepo + ((size_t)kb * 192 + l15) * 32 + q4 * 8;
        #pragma unroll
        for (int nt = 0; nt < 12; ++nt) {
            const bf16x8 bb = *(const bf16x8*)(wp + (size_t)nt * 16 * 32);
            acc[nt] = __builtin_amdgcn_mfma_f32_16x16x32_bf16(a, bb, acc[nt], 0, 0, 0);
        }
    }

    const int rw0 = rowbase + wave * 16 + q4 * 4;
    float sum[4] = {0.f, 0.f, 0.f, 0.f}, ssum[4] = {0.f, 0.f, 0.f, 0.f};
    #pragma unroll
    for (int nt = 0; nt < 12; ++nt) {
        const int col = nt * 16 + l15;
        const float bod = bo[col];
        #pragma unroll
        for (int reg = 0; reg < 4; ++reg) {
            const float v = acc[nt][reg] + bod + x[(size_t)(rw0 + reg) * D_ + col];
            acc[nt][reg] = v;
            x2b[(size_t)(rw0 + reg) * D_ + col] = f2b(v);
            sum[reg] += v; ssum[reg] += v * v;
        }
    }
    #pragma unroll
    for (int m = 1; m <= 8; m <<= 1) {
        #pragma unroll
        for (int reg = 0; reg < 4; ++reg) {
            sum[reg]  += __shfl_xor(sum[reg], m, 64);
            ssum[reg] += __shfl_xor(ssum[reg], m, 64);
        }
    }
    float mean[4], rs[4];
    #pragma unroll
    for (int reg = 0; reg < 4; ++reg) {
        mean[reg] = sum[reg] * (1.0f / 192.0f);
        const float var = ssum[reg] * (1.0f / 192.0f) - mean[reg] * mean[reg];
        rs[reg] = rsqrtf(var + EPS_);
    }
    #pragma unroll
    for (int nt = 0; nt < 12; ++nt) {
        const int col = nt * 16 + l15;
        const float g = g2[col], bb2 = lb2[col];
        #pragma unroll
        for (int reg = 0; reg < 4; ++reg)
            xn2b[(size_t)(rw0 + reg) * D_ + col] =
                f2b((acc[nt][reg] - mean[reg]) * rs[reg] * g + bb2);
    }
}

// ---------------------------------------------------------------------------
// K4/K5: conv as MFMA GEMM, higher arithmetic intensity: wave = all 4 M-tiles
// (64 rows) x 3 N-tiles (nt = wave*3..+2). Per kb-step: 4 A + 3 B loads feed
// 12 MFMAs (was 13 loads / 12 MFMAs); block weight traffic drops 4x.
// ---------------------------------------------------------------------------
template <int IS_CONV1>
__global__ __launch_bounds__(256) void k_conv_mfma(
    const bf16* __restrict__ act, const bf16* __restrict__ wrep,
    const float* __restrict__ bias, const bf16* __restrict__ x2b,
    bf16* __restrict__ outb, float* __restrict__ outf)
{
    const int wave = threadIdx.x >> 6, lane = threadIdx.x & 63;
    const int m16 = lane & 15, q = lane >> 4;
    const int rowbase = blockIdx.x * 64;

    f32x4 acc[4][3];
    #pragma unroll
    for (int mt = 0; mt < 4; ++mt)
        #pragma unroll
        for (int j = 0; j < 3; ++j) acc[mt][j] = (f32x4){0.f, 0.f, 0.f, 0.f};

    #pragma unroll
    for (int t = 0; t < 3; ++t) {
        #pragma unroll
        for (int c6 = 0; c6 < 6; ++c6) {
            const int kb = t * 6 + c6;
            bf16x8 a[4];
            #pragma unroll
            for (int mt = 0; mt < 4; ++mt) {
                const long long arow = (long long)rowbase + mt * 16 + m16 + t - 1;
                a[mt] = *(const bf16x8*)(act + arow * D_ + c6 * 32 + q * 8);
            }
            const bf16* wp = wrep + ((size_t)kb * 192 + m16) * 32 + q * 8;
            #pragma unroll
            for (int j = 0; j < 3; ++j) {
                const int nt = wave * 3 + j;
                const bf16x8 bfr = *(const bf16x8*)(wp + (size_t)nt * 16 * 32);
                #pragma unroll
                for (int mt = 0; mt < 4; ++mt)
                    acc[mt][j] = __builtin_amdgcn_mfma_f32_16x16x32_bf16(a[mt], bfr, acc[mt][j], 0, 0, 0);
            }
        }
    }

    #pragma unroll
    for (int j = 0; j < 3; ++j) {
        const int col = (wave * 3 + j) * 16 + m16;
        const float bd = bias[col];
        #pragma unroll
        for (int mt = 0; mt < 4; ++mt) {
            #pragma unroll
            for (int reg = 0; reg < 4; ++reg) {
                const int r = rowbase + mt * 16 + q * 4 + reg;
                const int m = r & (L_ - 1);
                const size_t idx = (size_t)r * D_ + col;
                if (IS_CONV1) {
                    float v = fmaxf(acc[mt][j][reg] + bd, 0.f);
                    if (m == 0 || m == L_ - 1) v = 0.f;
                    outb[idx] = f2b(v);
                } else {
                    float v = b2f(x2b[idx]);
                    if (m != 0 && m != L_ - 1) v += acc[mt][j][reg] + bd;
                    outf[idx] = v;
                }
            }
        }
    }
}

// ---------------------------------------------------------------------------
extern "C" void kernel_launch(void* const* d_in, const int* in_sizes, int n_in,
                              void* d_out, int out_size, void* d_ws, size_t ws_size,
                              hipStream_t stream)
{
    const float* x    = (const float*)d_in[0];
    const float* ln1g = (const float*)d_in[1];
    const float* ln1b = (const float*)d_in[2];
    const float* wq   = (const float*)d_in[3];
    const float* bq   = (const float*)d_in[4];
    const float* wk   = (const float*)d_in[5];
    const float* bk   = (const float*)d_in[6];
    const float* wv   = (const float*)d_in[7];
    const float* bv   = (const float*)d_in[8];
    const float* wo   = (const float*)d_in[9];
    const float* bo   = (const float*)d_in[10];
    const float* ln2g = (const float*)d_in[11];
    const float* ln2b = (const float*)d_in[12];
    const float* c1w  = (const float*)d_in[13];
    const float* c1b  = (const float*)d_in[14];
    const float* c2w  = (const float*)d_in[15];
    const float* c2b  = (const float*)d_in[16];

    const size_t ROWS = (size_t)16 * L_;            // 32768
    char* ws = (char*)d_ws;
    size_t off = 4096;                               // guard (conv row -1)
    bf16* xn2b = (bf16*)(ws + off); off += ROWS * D_ * 2;    // 12.6 MB
    off += 4096;                                     // guard
    bf16* hpb  = (bf16*)(ws + off); off += ROWS * D_ * 2;    // 12.6 MB
    off += 4096;                                     // guard
    bf16* x2b  = (bf16*)(ws + off); off += ROWS * D_ * 2;    // 12.6 MB
    f16* qb    = (f16*)(ws + off);   off += ROWS * HK_ * 2;  // 3.15 MB
    f16* kb    = (f16*)(ws + off);   off += ROWS * HK_ * 2;
    f16* vt    = (f16*)(ws + off);   off += (size_t)64 * 16 * 2048 * 2;   // 4.19 MB
    bf16* part_o = (bf16*)(ws + off); off += (size_t)64 * 8 * 2048 * 12 * 2; // 25.2 MB
    float* part_l = (float*)(ws + off); off += (size_t)64 * 8 * 2048 * 4;    //  4.2 MB
    bf16* wrep1 = (bf16*)(ws + off); off += 576 * 192 * 2;   // 221 KB
    bf16* wrep2 = (bf16*)(ws + off); off += 576 * 192 * 2;
    bf16* wrepq = (bf16*)(ws + off); off += 6 * 144 * 32 * 2;
    float* bias144 = (float*)(ws + off); off += 144 * 4;
    bf16* wrepo = (bf16*)(ws + off); off += 2 * 192 * 32 * 2; // total ~83 MB

    k_prep_all     <<<1021, 256, 0, stream>>>(c1w, c2w, wq, wk, wv, bq, bk, bv, wo,
                                              wrep1, wrep2, wrepq, bias144, wrepo);
    k_ln_qkv       <<< 512, 256, 0, stream>>>(x, ln1g, ln1b, wrepq, bias144, qb, kb, vt);
    k_attn_part    <<<64 * 36, 256, 0, stream>>>(qb, kb, vt, part_o, part_l);
    k_proj_ln2     <<< 512, 256, 0, stream>>>(x, part_o, part_l, wrepo, bo, ln2g, ln2b,
                                              x2b, xn2b);
    k_conv_mfma<1> <<< 512, 256, 0, stream>>>(xn2b, wrep1, c1b, nullptr, hpb, nullptr);
    k_conv_mfma<0> <<< 512, 256, 0, stream>>>(hpb, wrep2, c2b, x2b, nullptr, (float*)d_out);
}